// Round 1
// baseline (795.882 us; speedup 1.0000x reference)
//
#include <hip/hip_runtime.h>
#include <hip/hip_bf16.h>
#include <cstdint>

typedef unsigned short u16;
typedef __attribute__((__ext_vector_type__(4))) float f32x4;
typedef __attribute__((__ext_vector_type__(8))) __bf16 bf16x8;

#define DEV __device__ __forceinline__

static constexpr int Tt = 1024, Dd = 1024;
static constexpr int Mrows = 4096;  // B*T

DEV u16 f2bf(float f) {
  uint32_t u = __float_as_uint(f);
  u += 0x7fffu + ((u >> 16) & 1u);
  return (u16)(u >> 16);
}

DEV void gload_lds16(const void* g, void* l) {
  __builtin_amdgcn_global_load_lds(
      (__attribute__((address_space(1))) void*)(g),
      (__attribute__((address_space(3))) void*)(l), 16, 0, 0);
}

DEV float dot4(f32x4 a, f32x4 b) {
  return fmaf(a[0], b[0], fmaf(a[1], b[1], fmaf(a[2], b[2], a[3] * b[3])));
}

// ---------------- transpose fp32 [K,N] -> bf16 [N,K] ----------------
__global__ __launch_bounds__(256) void k_transpose_bf16(
    const float* __restrict__ W, u16* __restrict__ Wt, int K, int N) {
  __shared__ float tile[32][33];
  int n0 = blockIdx.x * 32, k0 = blockIdx.y * 32;
  int c = threadIdx.x & 31, r0 = threadIdx.x >> 5;
#pragma unroll
  for (int i = 0; i < 4; ++i) {
    int r = r0 + i * 8;
    tile[r][c] = W[(size_t)(k0 + r) * N + (n0 + c)];
  }
  __syncthreads();
#pragma unroll
  for (int i = 0; i < 4; ++i) {
    int r = r0 + i * 8;
    Wt[(size_t)(n0 + r) * K + (k0 + c)] = f2bf(tile[c][r]);
  }
}

// ---------------- LN1 + token shift + 6 mixes -> bf16 ----------------
__global__ __launch_bounds__(256) void k_ln_shift(
    const float* __restrict__ x, const float* __restrict__ w, const float* __restrict__ bias,
    const float* __restrict__ cr, const float* __restrict__ cw, const float* __restrict__ ck,
    const float* __restrict__ cv, const float* __restrict__ ca, const float* __restrict__ cg,
    u16* __restrict__ XR, u16* __restrict__ XW, u16* __restrict__ XK,
    u16* __restrict__ XV, u16* __restrict__ XA, u16* __restrict__ XG) {
  int row = blockIdx.x;
  int t = row & (Tt - 1);
  int tid = threadIdx.x;
  int col = tid * 4;
  const float* xc = x + (size_t)row * Dd + col;
  f32x4 c = *(const f32x4*)xc;
  f32x4 p = {0.f, 0.f, 0.f, 0.f};
  bool hasprev = (t != 0);
  if (hasprev) p = *(const f32x4*)(xc - Dd);
  float s1 = 0, s2 = 0, s3 = 0, s4 = 0;
#pragma unroll
  for (int j = 0; j < 4; ++j) {
    s1 += c[j]; s2 += c[j] * c[j];
    s3 += p[j]; s4 += p[j] * p[j];
  }
#pragma unroll
  for (int m = 1; m < 64; m <<= 1) {
    s1 += __shfl_xor(s1, m, 64); s2 += __shfl_xor(s2, m, 64);
    s3 += __shfl_xor(s3, m, 64); s4 += __shfl_xor(s4, m, 64);
  }
  __shared__ float red[4][4];
  int wid = tid >> 6;
  if ((tid & 63) == 0) { red[wid][0] = s1; red[wid][1] = s2; red[wid][2] = s3; red[wid][3] = s4; }
  __syncthreads();
  s1 = red[0][0] + red[1][0] + red[2][0] + red[3][0];
  s2 = red[0][1] + red[1][1] + red[2][1] + red[3][1];
  s3 = red[0][2] + red[1][2] + red[2][2] + red[3][2];
  s4 = red[0][3] + red[1][3] + red[2][3] + red[3][3];
  const float invD = 1.f / (float)Dd;
  float mc = s1 * invD, vc = s2 * invD - mc * mc;
  float rc = rsqrtf(vc + 1e-5f);
  float mp = s3 * invD, vp = s4 * invD - mp * mp;
  float rp = rsqrtf(vp + 1e-5f);
  size_t ob = (size_t)row * Dd + col;
#pragma unroll
  for (int j = 0; j < 4; ++j) {
    int cc = col + j;
    float wj = w[cc], bj = bias[cc];
    float xn = (c[j] - mc) * rc * wj + bj;
    float xp = hasprev ? ((p[j] - mp) * rp * wj + bj) : 0.f;
    float d = xp - xn;
    XR[ob + j] = f2bf(xn + d * cr[cc]);
    XW[ob + j] = f2bf(xn + d * cw[cc]);
    XK[ob + j] = f2bf(xn + d * ck[cc]);
    XV[ob + j] = f2bf(xn + d * cv[cc]);
    XA[ob + j] = f2bf(xn + d * ca[cc]);
    XG[ob + j] = f2bf(xn + d * cg[cc]);
  }
}

// ---------------- bf16 MFMA GEMM: C[M,N] = A[M,K] @ Bt[N,K]^T ----------------
// EPI: 0=f32  1=tanh->bf16  2=sigmoid->bf16  3=bf16
//      4=exp(-softplus(-(w0+y)))-0.5 == e^-.5*sigmoid(w0+y) ->f32
//      5=sigmoid(a0+y)->f32  6=y+res->f32  7=y+bias+res->f32
template <int BN, int EPI>
__global__ __launch_bounds__(256) void k_gemm_bt(
    const u16* __restrict__ A, const u16* __restrict__ Bt,
    float* __restrict__ Cf, u16* __restrict__ Cb,
    const float* __restrict__ aux, const float* __restrict__ res,
    int Ndim, int K) {
  constexpr int BM = 128;
  constexpr int MR = 4;
  constexpr int NR = BN / 32;
  __shared__ __align__(16) u16 lsA[BM * 32];
  __shared__ __align__(16) u16 lsB[BN * 32];
  int tid = threadIdx.x;
  int wid = tid >> 6, lane = tid & 63;
  int wr = wid >> 1, wc = wid & 1;
  int lrow = lane & 15, lk = lane >> 4;
  int m0 = blockIdx.y * BM, n0 = blockIdx.x * BN;
  f32x4 acc[MR][NR];
#pragma unroll
  for (int m = 0; m < MR; ++m)
#pragma unroll
    for (int n = 0; n < NR; ++n) acc[m][n] = (f32x4){0.f, 0.f, 0.f, 0.f};

  for (int kt = 0; kt < K; kt += 32) {
#pragma unroll
    for (int u = 0; u < BM / 64; ++u) {
      int e = u * 256 + tid;
      int row = e >> 2, kc = (e & 3) * 8;
      gload_lds16(A + (size_t)(m0 + row) * K + kt + kc, lsA + (size_t)(u * 256 + wid * 64) * 8);
    }
#pragma unroll
    for (int u = 0; u < BN / 64; ++u) {
      int e = u * 256 + tid;
      int row = e >> 2, kc = (e & 3) * 8;
      gload_lds16(Bt + (size_t)(n0 + row) * K + kt + kc, lsB + (size_t)(u * 256 + wid * 64) * 8);
    }
    __syncthreads();
    bf16x8 af[MR], bfv[NR];
#pragma unroll
    for (int m = 0; m < MR; ++m)
      af[m] = *(const bf16x8*)&lsA[(wr * 64 + m * 16 + lrow) * 32 + lk * 8];
#pragma unroll
    for (int n = 0; n < NR; ++n)
      bfv[n] = *(const bf16x8*)&lsB[(wc * (BN / 2) + n * 16 + lrow) * 32 + lk * 8];
#pragma unroll
    for (int m = 0; m < MR; ++m)
#pragma unroll
      for (int n = 0; n < NR; ++n)
        acc[m][n] = __builtin_amdgcn_mfma_f32_16x16x32_bf16(af[m], bfv[n], acc[m][n], 0, 0, 0);
    __syncthreads();
  }
#pragma unroll
  for (int m = 0; m < MR; ++m) {
    int rbase = m0 + wr * 64 + m * 16 + lk * 4;
#pragma unroll
    for (int n = 0; n < NR; ++n) {
      int col = n0 + wc * (BN / 2) + n * 16 + lrow;
#pragma unroll
      for (int j = 0; j < 4; ++j) {
        float v = acc[m][n][j];
        size_t idx = (size_t)(rbase + j) * Ndim + col;
        if constexpr (EPI == 0) { Cf[idx] = v; }
        else if constexpr (EPI == 1) { Cb[idx] = f2bf(tanhf(v)); }
        else if constexpr (EPI == 2) { Cb[idx] = f2bf(1.f / (1.f + __expf(-v))); }
        else if constexpr (EPI == 3) { Cb[idx] = f2bf(v); }
        else if constexpr (EPI == 4) { Cf[idx] = 0.60653065971f / (1.f + __expf(-(aux[col] + v))); }
        else if constexpr (EPI == 5) { Cf[idx] = 1.f / (1.f + __expf(-(aux[col] + v))); }
        else if constexpr (EPI == 6) { Cf[idx] = v + res[idx]; }
        else { Cf[idx] = v + aux[col] + res[idx]; }
      }
    }
  }
}

// ---------------- prep: kk normalize, kka, k' ----------------
__global__ __launch_bounds__(256) void k_prep(
    const float* __restrict__ KRAW, const float* __restrict__ Aa,
    const float* __restrict__ k_k, const float* __restrict__ k_a,
    float* __restrict__ KK, float* __restrict__ KKA, float* __restrict__ KP) {
  int row = blockIdx.x;
  int tid = threadIdx.x;
  int col = tid * 4;
  size_t idx = (size_t)row * Dd + col;
  f32x4 kr = *(const f32x4*)(KRAW + idx);
  f32x4 av = *(const f32x4*)(Aa + idx);
  f32x4 kkc = *(const f32x4*)(k_k + col);
  f32x4 kac = *(const f32x4*)(k_a + col);
  f32x4 kk0 = kr * kkc;
  float ss = kk0[0] * kk0[0] + kk0[1] * kk0[1] + kk0[2] * kk0[2] + kk0[3] * kk0[3];
#pragma unroll
  for (int m = 1; m < 16; m <<= 1) ss += __shfl_xor(ss, m, 64);
  float inv = 1.f / fmaxf(sqrtf(ss), 1e-12f);
  f32x4 kk = kk0 * inv;
  f32x4 one = {1.f, 1.f, 1.f, 1.f};
  *(f32x4*)(KK + idx) = kk;
  *(f32x4*)(KKA + idx) = kk * av;
  *(f32x4*)(KP + idx) = kr * (one + (av - one) * kac);
}

// ---------------- sequential delta-rule scan ----------------
// grid 64 = (b,h); 4 waves; lane (vq,kq): v = wid*16+vq owns S[v][kq*16 .. +16)
__global__ __launch_bounds__(256) void k_scan(
    const float* __restrict__ R, const float* __restrict__ WD, const float* __restrict__ KP,
    const float* __restrict__ KK, const float* __restrict__ KKA, const float* __restrict__ V,
    float* __restrict__ O) {
  __shared__ float lds[6][32][64];
  int bh = blockIdx.x;
  int b = bh >> 4, h = bh & 15;
  int tid = threadIdx.x;
  int wid = tid >> 6, lane = tid & 63;
  int vq = lane & 15, kq = lane >> 4;
  int vrow = wid * 16 + vq;
  int ko = kq * 16;
  size_t rowbase = ((size_t)b * Tt) * Dd + h * 64;
  f32x4 S0 = {0, 0, 0, 0}, S1 = S0, S2 = S0, S3 = S0;
  for (int c0 = 0; c0 < Tt; c0 += 32) {
    const float* ptrs[6] = {R, WD, KP, KK, KKA, V};
#pragma unroll
    for (int arr = 0; arr < 6; ++arr) {
#pragma unroll
      for (int u = 0; u < 2; ++u) {
        int e = u * 256 + tid;
        int tt = e >> 4, part = (e & 15) * 4;
        *(f32x4*)&lds[arr][tt][part] =
            *(const f32x4*)(ptrs[arr] + rowbase + (size_t)(c0 + tt) * Dd + part);
      }
    }
    __syncthreads();
    for (int tt = 0; tt < 32; ++tt) {
      const float* Lkk = &lds[3][tt][ko];
      f32x4 kk0 = *(const f32x4*)(Lkk), kk1 = *(const f32x4*)(Lkk + 4),
            kk2 = *(const f32x4*)(Lkk + 8), kk3 = *(const f32x4*)(Lkk + 12);
      float sab = (dot4(S0, kk0) + dot4(S1, kk1)) + (dot4(S2, kk2) + dot4(S3, kk3));
      sab += __shfl_xor(sab, 16, 64);
      sab += __shfl_xor(sab, 32, 64);
      const float* Lwd = &lds[1][tt][ko];
      f32x4 wd0 = *(const f32x4*)(Lwd), wd1 = *(const f32x4*)(Lwd + 4),
            wd2 = *(const f32x4*)(Lwd + 8), wd3 = *(const f32x4*)(Lwd + 12);
      const float* Lka = &lds[4][tt][ko];
      f32x4 ka0 = *(const f32x4*)(Lka), ka1 = *(const f32x4*)(Lka + 4),
            ka2 = *(const f32x4*)(Lka + 8), ka3 = *(const f32x4*)(Lka + 12);
      const float* Lkp = &lds[2][tt][ko];
      f32x4 kp0 = *(const f32x4*)(Lkp), kp1 = *(const f32x4*)(Lkp + 4),
            kp2 = *(const f32x4*)(Lkp + 8), kp3 = *(const f32x4*)(Lkp + 12);
      float vt = lds[5][tt][vrow];
      S0 = S0 * wd0 - sab * ka0 + vt * kp0;
      S1 = S1 * wd1 - sab * ka1 + vt * kp1;
      S2 = S2 * wd2 - sab * ka2 + vt * kp2;
      S3 = S3 * wd3 - sab * ka3 + vt * kp3;
      const float* Lr = &lds[0][tt][ko];
      f32x4 r0 = *(const f32x4*)(Lr), r1 = *(const f32x4*)(Lr + 4),
            r2 = *(const f32x4*)(Lr + 8), r3 = *(const f32x4*)(Lr + 12);
      float o = (dot4(S0, r0) + dot4(S1, r1)) + (dot4(S2, r2) + dot4(S3, r3));
      o += __shfl_xor(o, 16, 64);
      o += __shfl_xor(o, 32, 64);
      if (kq == 0) O[rowbase + (size_t)(c0 + tt) * Dd + vrow] = o;
    }
    __syncthreads();
  }
}

// ---------------- per-head groupnorm + bonus + gate -> bf16 ----------------
__global__ __launch_bounds__(256) void k_gn_gate(
    const float* __restrict__ O, const float* __restrict__ R, const float* __restrict__ KP,
    const float* __restrict__ V, const float* __restrict__ G,
    const float* __restrict__ r_k, const float* __restrict__ gn_w, const float* __restrict__ gn_b,
    u16* __restrict__ GT) {
  int row = blockIdx.x;
  int tid = threadIdx.x;
  int col = tid * 4;
  size_t idx = (size_t)row * Dd + col;
  f32x4 o = *(const f32x4*)(O + idx), r = *(const f32x4*)(R + idx),
        kp = *(const f32x4*)(KP + idx), v = *(const f32x4*)(V + idx),
        g = *(const f32x4*)(G + idx);
  f32x4 rk = *(const f32x4*)(r_k + col), gw = *(const f32x4*)(gn_w + col),
        gb = *(const f32x4*)(gn_b + col);
  float so = 0, so2 = 0, sb = 0;
#pragma unroll
  for (int j = 0; j < 4; ++j) {
    so += o[j]; so2 += o[j] * o[j]; sb += r[j] * kp[j] * rk[j];
  }
#pragma unroll
  for (int m = 1; m < 16; m <<= 1) {
    so += __shfl_xor(so, m, 64);
    so2 += __shfl_xor(so2, m, 64);
    sb += __shfl_xor(sb, m, 64);
  }
  float mu = so * (1.f / 64.f);
  float var = so2 * (1.f / 64.f) - mu * mu;
  float rs = rsqrtf(var + 64e-5f);
#pragma unroll
  for (int j = 0; j < 4; ++j) {
    float on = (o[j] - mu) * rs * gw[j] + gb[j] + sb * v[j];
    GT[idx + j] = f2bf(on * g[j]);
  }
}

// ---------------- plain LN -> bf16 ----------------
__global__ __launch_bounds__(256) void k_ln(
    const float* __restrict__ X, const float* __restrict__ w, const float* __restrict__ bias,
    u16* __restrict__ OUT) {
  int row = blockIdx.x;
  int tid = threadIdx.x;
  int col = tid * 4;
  size_t idx = (size_t)row * Dd + col;
  f32x4 c = *(const f32x4*)(X + idx);
  float s1 = 0, s2 = 0;
#pragma unroll
  for (int j = 0; j < 4; ++j) { s1 += c[j]; s2 += c[j] * c[j]; }
#pragma unroll
  for (int m = 1; m < 64; m <<= 1) { s1 += __shfl_xor(s1, m, 64); s2 += __shfl_xor(s2, m, 64); }
  __shared__ float red[4][2];
  int wid = tid >> 6;
  if ((tid & 63) == 0) { red[wid][0] = s1; red[wid][1] = s2; }
  __syncthreads();
  s1 = red[0][0] + red[1][0] + red[2][0] + red[3][0];
  s2 = red[0][1] + red[1][1] + red[2][1] + red[3][1];
  const float invD = 1.f / (float)Dd;
  float mc = s1 * invD;
  float rc = rsqrtf(s2 * invD - mc * mc + 1e-5f);
#pragma unroll
  for (int j = 0; j < 4; ++j)
    OUT[idx + j] = f2bf((c[j] - mc) * rc * w[col + j] + bias[col + j]);
}

extern "C" void kernel_launch(void* const* d_in, const int* in_sizes, int n_in,
                              void* d_out, int out_size, void* d_ws, size_t ws_size,
                              hipStream_t stream) {
  const float* x    = (const float*)d_in[0];
  const float* ln1w = (const float*)d_in[1];
  const float* ln1b = (const float*)d_in[2];
  const float* ln2w = (const float*)d_in[3];
  const float* ln2b = (const float*)d_in[4];
  const float* xr_c = (const float*)d_in[5];
  const float* xw_c = (const float*)d_in[6];
  const float* xk_c = (const float*)d_in[7];
  const float* xv_c = (const float*)d_in[8];
  const float* xa_c = (const float*)d_in[9];
  const float* xg_c = (const float*)d_in[10];
  const float* Wr   = (const float*)d_in[11];
  const float* Wk   = (const float*)d_in[12];
  const float* Wv   = (const float*)d_in[13];
  const float* w0   = (const float*)d_in[14];
  const float* w1   = (const float*)d_in[15];
  const float* w2   = (const float*)d_in[16];
  const float* a0   = (const float*)d_in[17];
  const float* a1   = (const float*)d_in[18];
  const float* a2   = (const float*)d_in[19];
  const float* g1   = (const float*)d_in[20];
  const float* g2   = (const float*)d_in[21];
  const float* k_k  = (const float*)d_in[22];
  const float* k_a  = (const float*)d_in[23];
  const float* r_k  = (const float*)d_in[24];
  const float* gnw  = (const float*)d_in[25];
  const float* gnb  = (const float*)d_in[26];
  const float* Wo   = (const float*)d_in[27];
  const float* mlpw = (const float*)d_in[28];
  const float* mlpb = (const float*)d_in[29];

  char* ws = (char*)d_ws;
  const size_t MBy = 1024 * 1024;
  u16* WT_R  = (u16*)(ws + 0 * MBy);
  u16* WT_K  = (u16*)(ws + 2 * MBy);
  u16* WT_V  = (u16*)(ws + 4 * MBy);
  u16* WT_O  = (u16*)(ws + 6 * MBy);
  u16* WT_M  = (u16*)(ws + 8 * MBy);
  u16* WT_w1 = (u16*)(ws + 10 * MBy);
  u16* WT_a1 = (u16*)(ws + 10 * MBy + 128 * 1024);
  u16* WT_g1 = (u16*)(ws + 10 * MBy + 256 * 1024);
  u16* WT_w2 = (u16*)(ws + 10 * MBy + 512 * 1024);
  u16* WT_a2 = (u16*)(ws + 10 * MBy + 640 * 1024);
  u16* WT_g2 = (u16*)(ws + 10 * MBy + 768 * 1024);
  u16* XR = (u16*)(ws + 12 * MBy);
  u16* XW = (u16*)(ws + 20 * MBy);
  u16* XK = (u16*)(ws + 28 * MBy);
  u16* XV = (u16*)(ws + 36 * MBy);
  u16* XA = (u16*)(ws + 44 * MBy);
  u16* XG = (u16*)(ws + 52 * MBy);
  float* Rf   = (float*)(ws + 60 * MBy);
  float* KRAW = (float*)(ws + 76 * MBy);
  float* WDf  = (float*)(ws + 92 * MBy);
  float* Af   = (float*)(ws + 108 * MBy);
  float* Gf   = (float*)(ws + 124 * MBy);
  // overlays (X6 dead after first-stage GEMMs, etc.)
  float* KKf  = (float*)(ws + 12 * MBy);
  float* KKAf = (float*)(ws + 28 * MBy);
  float* KPf  = (float*)(ws + 44 * MBy);
  float* Of   = (float*)(ws + 76 * MBy);   // over KRAW (dead after prep)
  float* X1   = (float*)(ws + 92 * MBy);   // over WDf (dead after scan)
  u16* GT  = (u16*)(ws + 108 * MBy);       // over Af  (dead after prep)
  u16* XN2 = (u16*)(ws + 124 * MBy);       // over Gf  (dead after gn_gate)
  u16* HW = (u16*)(ws + 140 * MBy);
  u16* HA = (u16*)(ws + 140 * MBy + 512 * 1024);
  u16* HG = (u16*)(ws + 141 * MBy);
  float* OUT_X = (float*)d_out;
  float* OUT_V = (float*)d_out + (size_t)Mrows * Dd;

  dim3 blk(256);
  k_transpose_bf16<<<dim3(32, 32), blk, 0, stream>>>(Wr, WT_R, 1024, 1024);
  k_transpose_bf16<<<dim3(32, 32), blk, 0, stream>>>(Wk, WT_K, 1024, 1024);
  k_transpose_bf16<<<dim3(32, 32), blk, 0, stream>>>(Wv, WT_V, 1024, 1024);
  k_transpose_bf16<<<dim3(32, 32), blk, 0, stream>>>(Wo, WT_O, 1024, 1024);
  k_transpose_bf16<<<dim3(32, 32), blk, 0, stream>>>(mlpw, WT_M, 1024, 1024);
  k_transpose_bf16<<<dim3(2, 32), blk, 0, stream>>>(w1, WT_w1, 1024, 64);
  k_transpose_bf16<<<dim3(2, 32), blk, 0, stream>>>(a1, WT_a1, 1024, 64);
  k_transpose_bf16<<<dim3(4, 32), blk, 0, stream>>>(g1, WT_g1, 1024, 128);
  k_transpose_bf16<<<dim3(32, 2), blk, 0, stream>>>(w2, WT_w2, 64, 1024);
  k_transpose_bf16<<<dim3(32, 2), blk, 0, stream>>>(a2, WT_a2, 64, 1024);
  k_transpose_bf16<<<dim3(32, 4), blk, 0, stream>>>(g2, WT_g2, 128, 1024);

  k_ln_shift<<<Mrows, blk, 0, stream>>>(x, ln1w, ln1b, xr_c, xw_c, xk_c, xv_c, xa_c, xg_c,
                                        XR, XW, XK, XV, XA, XG);

  k_gemm_bt<128, 0><<<dim3(8, 32), blk, 0, stream>>>(XR, WT_R, Rf, nullptr, nullptr, nullptr, 1024, 1024);
  k_gemm_bt<128, 0><<<dim3(8, 32), blk, 0, stream>>>(XK, WT_K, KRAW, nullptr, nullptr, nullptr, 1024, 1024);
  k_gemm_bt<128, 0><<<dim3(8, 32), blk, 0, stream>>>(XV, WT_V, OUT_V, nullptr, nullptr, nullptr, 1024, 1024);
  k_gemm_bt<64, 1><<<dim3(1, 32), blk, 0, stream>>>(XW, WT_w1, nullptr, HW, nullptr, nullptr, 64, 1024);
  k_gemm_bt<64, 3><<<dim3(1, 32), blk, 0, stream>>>(XA, WT_a1, nullptr, HA, nullptr, nullptr, 64, 1024);
  k_gemm_bt<128, 2><<<dim3(1, 32), blk, 0, stream>>>(XG, WT_g1, nullptr, HG, nullptr, nullptr, 128, 1024);
  k_gemm_bt<128, 4><<<dim3(8, 32), blk, 0, stream>>>(HW, WT_w2, WDf, nullptr, w0, nullptr, 1024, 64);
  k_gemm_bt<128, 5><<<dim3(8, 32), blk, 0, stream>>>(HA, WT_a2, Af, nullptr, a0, nullptr, 1024, 64);
  k_gemm_bt<128, 0><<<dim3(8, 32), blk, 0, stream>>>(HG, WT_g2, Gf, nullptr, nullptr, nullptr, 1024, 128);

  k_prep<<<Mrows, blk, 0, stream>>>(KRAW, Af, k_k, k_a, KKf, KKAf, KPf);
  k_scan<<<64, blk, 0, stream>>>(Rf, WDf, KPf, KKf, KKAf, OUT_V, Of);
  k_gn_gate<<<Mrows, blk, 0, stream>>>(Of, Rf, KPf, OUT_V, Gf, r_k, gnw, gnb, GT);
  k_gemm_bt<128, 6><<<dim3(8, 32), blk, 0, stream>>>(GT, WT_O, X1, nullptr, nullptr, x, 1024, 1024);
  k_ln<<<Mrows, blk, 0, stream>>>(X1, ln2w, ln2b, XN2);
  k_gemm_bt<128, 7><<<dim3(8, 32), blk, 0, stream>>>(XN2, WT_M, OUT_X, nullptr, mlpb, X1, 1024, 1024);
}

// Round 2
// 616.273 us; speedup vs baseline: 1.2914x; 1.2914x over previous
//
#include <hip/hip_runtime.h>
#include <hip/hip_bf16.h>
#include <cstdint>

typedef unsigned short u16;
typedef __attribute__((__ext_vector_type__(4))) float f32x4;
typedef __attribute__((__ext_vector_type__(8))) __bf16 bf16x8;

#define DEV __device__ __forceinline__

static constexpr int Tt = 1024, Dd = 1024;
static constexpr int Mrows = 4096;  // B*T

DEV u16 f2bf(float f) {
  uint32_t u = __float_as_uint(f);
  u += 0x7fffu + ((u >> 16) & 1u);
  return (u16)(u >> 16);
}

DEV void gload_lds16(const void* g, void* l) {
  __builtin_amdgcn_global_load_lds(
      (__attribute__((address_space(1))) void*)(g),
      (__attribute__((address_space(3))) void*)(l), 16, 0, 0);
}

DEV float dot4(f32x4 a, f32x4 b) {
  return fmaf(a[0], b[0], fmaf(a[1], b[1], fmaf(a[2], b[2], a[3] * b[3])));
}

// ---------------- transpose fp32 [K,N] -> bf16 [N,K] ----------------
__global__ __launch_bounds__(256) void k_transpose_bf16(
    const float* __restrict__ W, u16* __restrict__ Wt, int K, int N) {
  __shared__ float tile[32][33];
  int n0 = blockIdx.x * 32, k0 = blockIdx.y * 32;
  int c = threadIdx.x & 31, r0 = threadIdx.x >> 5;
#pragma unroll
  for (int i = 0; i < 4; ++i) {
    int r = r0 + i * 8;
    tile[r][c] = W[(size_t)(k0 + r) * N + (n0 + c)];
  }
  __syncthreads();
#pragma unroll
  for (int i = 0; i < 4; ++i) {
    int r = r0 + i * 8;
    Wt[(size_t)(n0 + r) * K + (k0 + c)] = f2bf(tile[c][r]);
  }
}

// ---------------- LN1 + token shift + 6 mixes -> bf16 ----------------
__global__ __launch_bounds__(256) void k_ln_shift(
    const float* __restrict__ x, const float* __restrict__ w, const float* __restrict__ bias,
    const float* __restrict__ cr, const float* __restrict__ cw, const float* __restrict__ ck,
    const float* __restrict__ cv, const float* __restrict__ ca, const float* __restrict__ cg,
    u16* __restrict__ XR, u16* __restrict__ XW, u16* __restrict__ XK,
    u16* __restrict__ XV, u16* __restrict__ XA, u16* __restrict__ XG) {
  int row = blockIdx.x;
  int t = row & (Tt - 1);
  int tid = threadIdx.x;
  int col = tid * 4;
  const float* xc = x + (size_t)row * Dd + col;
  f32x4 c = *(const f32x4*)xc;
  f32x4 p = {0.f, 0.f, 0.f, 0.f};
  bool hasprev = (t != 0);
  if (hasprev) p = *(const f32x4*)(xc - Dd);
  float s1 = 0, s2 = 0, s3 = 0, s4 = 0;
#pragma unroll
  for (int j = 0; j < 4; ++j) {
    s1 += c[j]; s2 += c[j] * c[j];
    s3 += p[j]; s4 += p[j] * p[j];
  }
#pragma unroll
  for (int m = 1; m < 64; m <<= 1) {
    s1 += __shfl_xor(s1, m, 64); s2 += __shfl_xor(s2, m, 64);
    s3 += __shfl_xor(s3, m, 64); s4 += __shfl_xor(s4, m, 64);
  }
  __shared__ float red[4][4];
  int wid = tid >> 6;
  if ((tid & 63) == 0) { red[wid][0] = s1; red[wid][1] = s2; red[wid][2] = s3; red[wid][3] = s4; }
  __syncthreads();
  s1 = red[0][0] + red[1][0] + red[2][0] + red[3][0];
  s2 = red[0][1] + red[1][1] + red[2][1] + red[3][1];
  s3 = red[0][2] + red[1][2] + red[2][2] + red[3][2];
  s4 = red[0][3] + red[1][3] + red[2][3] + red[3][3];
  const float invD = 1.f / (float)Dd;
  float mc = s1 * invD, vc = s2 * invD - mc * mc;
  float rc = rsqrtf(vc + 1e-5f);
  float mp = s3 * invD, vp = s4 * invD - mp * mp;
  float rp = rsqrtf(vp + 1e-5f);
  size_t ob = (size_t)row * Dd + col;
#pragma unroll
  for (int j = 0; j < 4; ++j) {
    int cc = col + j;
    float wj = w[cc], bj = bias[cc];
    float xn = (c[j] - mc) * rc * wj + bj;
    float xp = hasprev ? ((p[j] - mp) * rp * wj + bj) : 0.f;
    float d = xp - xn;
    XR[ob + j] = f2bf(xn + d * cr[cc]);
    XW[ob + j] = f2bf(xn + d * cw[cc]);
    XK[ob + j] = f2bf(xn + d * ck[cc]);
    XV[ob + j] = f2bf(xn + d * cv[cc]);
    XA[ob + j] = f2bf(xn + d * ca[cc]);
    XG[ob + j] = f2bf(xn + d * cg[cc]);
  }
}

// ---------------- bf16 MFMA GEMM: C[M,N] = A[M,K] @ Bt[N,K]^T ----------------
// EPI: 0=f32  1=tanh->bf16  2=sigmoid->bf16  3=bf16
//      4=exp(-softplus(-(w0+y)))-0.5 == e^-.5*sigmoid(w0+y) ->f32
//      5=sigmoid(a0+y)->f32  6=y+res->f32  7=y+bias+res->f32
template <int BN, int EPI>
__global__ __launch_bounds__(256) void k_gemm_bt(
    const u16* __restrict__ A, const u16* __restrict__ Bt,
    float* __restrict__ Cf, u16* __restrict__ Cb,
    const float* __restrict__ aux, const float* __restrict__ res,
    int Ndim, int K) {
  constexpr int BM = 128;
  constexpr int MR = 4;
  constexpr int NR = BN / 32;
  __shared__ __align__(16) u16 lsA[BM * 32];
  __shared__ __align__(16) u16 lsB[BN * 32];
  int tid = threadIdx.x;
  int wid = tid >> 6, lane = tid & 63;
  int wr = wid >> 1, wc = wid & 1;
  int lrow = lane & 15, lk = lane >> 4;
  int m0 = blockIdx.y * BM, n0 = blockIdx.x * BN;
  f32x4 acc[MR][NR];
#pragma unroll
  for (int m = 0; m < MR; ++m)
#pragma unroll
    for (int n = 0; n < NR; ++n) acc[m][n] = (f32x4){0.f, 0.f, 0.f, 0.f};

  for (int kt = 0; kt < K; kt += 32) {
#pragma unroll
    for (int u = 0; u < BM / 64; ++u) {
      int e = u * 256 + tid;
      int row = e >> 2, kc = (e & 3) * 8;
      gload_lds16(A + (size_t)(m0 + row) * K + kt + kc, lsA + (size_t)(u * 256 + wid * 64) * 8);
    }
#pragma unroll
    for (int u = 0; u < BN / 64; ++u) {
      int e = u * 256 + tid;
      int row = e >> 2, kc = (e & 3) * 8;
      gload_lds16(Bt + (size_t)(n0 + row) * K + kt + kc, lsB + (size_t)(u * 256 + wid * 64) * 8);
    }
    __syncthreads();
    bf16x8 af[MR], bfv[NR];
#pragma unroll
    for (int m = 0; m < MR; ++m)
      af[m] = *(const bf16x8*)&lsA[(wr * 64 + m * 16 + lrow) * 32 + lk * 8];
#pragma unroll
    for (int n = 0; n < NR; ++n)
      bfv[n] = *(const bf16x8*)&lsB[(wc * (BN / 2) + n * 16 + lrow) * 32 + lk * 8];
#pragma unroll
    for (int m = 0; m < MR; ++m)
#pragma unroll
      for (int n = 0; n < NR; ++n)
        acc[m][n] = __builtin_amdgcn_mfma_f32_16x16x32_bf16(af[m], bfv[n], acc[m][n], 0, 0, 0);
    __syncthreads();
  }
#pragma unroll
  for (int m = 0; m < MR; ++m) {
    int rbase = m0 + wr * 64 + m * 16 + lk * 4;
#pragma unroll
    for (int n = 0; n < NR; ++n) {
      int col = n0 + wc * (BN / 2) + n * 16 + lrow;
#pragma unroll
      for (int j = 0; j < 4; ++j) {
        float v = acc[m][n][j];
        size_t idx = (size_t)(rbase + j) * Ndim + col;
        if constexpr (EPI == 0) { Cf[idx] = v; }
        else if constexpr (EPI == 1) { Cb[idx] = f2bf(tanhf(v)); }
        else if constexpr (EPI == 2) { Cb[idx] = f2bf(1.f / (1.f + __expf(-v))); }
        else if constexpr (EPI == 3) { Cb[idx] = f2bf(v); }
        else if constexpr (EPI == 4) { Cf[idx] = 0.60653065971f / (1.f + __expf(-(aux[col] + v))); }
        else if constexpr (EPI == 5) { Cf[idx] = 1.f / (1.f + __expf(-(aux[col] + v))); }
        else if constexpr (EPI == 6) { Cf[idx] = v + res[idx]; }
        else { Cf[idx] = v + aux[col] + res[idx]; }
      }
    }
  }
}

// ---------------- prep: kk normalize, kka, k' ----------------
__global__ __launch_bounds__(256) void k_prep(
    const float* __restrict__ KRAW, const float* __restrict__ Aa,
    const float* __restrict__ k_k, const float* __restrict__ k_a,
    float* __restrict__ KK, float* __restrict__ KKA, float* __restrict__ KP) {
  int row = blockIdx.x;
  int tid = threadIdx.x;
  int col = tid * 4;
  size_t idx = (size_t)row * Dd + col;
  f32x4 kr = *(const f32x4*)(KRAW + idx);
  f32x4 av = *(const f32x4*)(Aa + idx);
  f32x4 kkc = *(const f32x4*)(k_k + col);
  f32x4 kac = *(const f32x4*)(k_a + col);
  f32x4 kk0 = kr * kkc;
  float ss = kk0[0] * kk0[0] + kk0[1] * kk0[1] + kk0[2] * kk0[2] + kk0[3] * kk0[3];
#pragma unroll
  for (int m = 1; m < 16; m <<= 1) ss += __shfl_xor(ss, m, 64);
  float inv = 1.f / fmaxf(sqrtf(ss), 1e-12f);
  f32x4 kk = kk0 * inv;
  f32x4 one = {1.f, 1.f, 1.f, 1.f};
  *(f32x4*)(KK + idx) = kk;
  *(f32x4*)(KKA + idx) = kk * av;
  *(f32x4*)(KP + idx) = kr * (one + (av - one) * kac);
}

// ---------------- sequential delta-rule scan, v-split ----------------
// 256 wgs = 64 (b,h) x 4 v-groups of 16 rows. 256T = 4 waves x 4 rows.
// lane: vq = (lane>>2)&3 (row within wave), kq = (lane&3)|((lane>>2)&12)
// (k-reduce lanes differ in bits {0,1,4,5} -> shfl_xor masks 1,2,16,32).
// Per-lane state: S[row][kq*4 .. kq*4+4) as one f32x4.
// o_t = S_old.(wd*r) - sab*(kka.r) + v_t*(kp.r)  (scalars per step from LDS).
__global__ __launch_bounds__(256) void k_scan(
    const float* __restrict__ R, const float* __restrict__ WD, const float* __restrict__ KP,
    const float* __restrict__ KK, const float* __restrict__ KKA, const float* __restrict__ V,
    float* __restrict__ O) {
  __shared__ __align__(16) float buf[2][5][32][64];  // KK,WD,R,KKA,KP
  __shared__ __align__(16) float vtb[2][32][16];
  __shared__ float scal[2][32][2];
  // XCD-chunked swizzle: 4 v-groups of one (b,h) land on the same XCD.
  int sw = (blockIdx.x & 7) * 32 + (blockIdx.x >> 3);
  int bh = sw >> 2, vg = sw & 3;
  int b = bh >> 4, h = bh & 15;
  int tid = threadIdx.x;
  int wid = tid >> 6, lane = tid & 63;
  int vq = (lane >> 2) & 3;
  int kq = (lane & 3) | ((lane >> 2) & 12);
  int row = vg * 16 + wid * 4 + vq;       // v in [0,64)
  int koff = kq * 4;
  size_t rowbase = ((size_t)b * Tt) * Dd + h * 64;

  const float* ptrs[5] = {KK, WD, R, KKA, KP};
  auto stage = [&](int c, int nb) {
#pragma unroll
    for (int arr = 0; arr < 5; ++arr) {
#pragma unroll
      for (int u = 0; u < 2; ++u) {
        int e = u * 256 + tid;
        int tt = e >> 4, k4 = (e & 15) * 4;
        gload_lds16(ptrs[arr] + rowbase + (size_t)(c * 32 + tt) * Dd + k4,
                    &buf[nb][arr][0][0] + (size_t)e * 4);
      }
    }
    if (tid < 128) {
      gload_lds16(V + rowbase + (size_t)(c * 32 + (tid >> 2)) * Dd + vg * 16 + (tid & 3) * 4,
                  &vtb[nb][0][0] + (size_t)tid * 4);
    }
  };

  f32x4 S = {0.f, 0.f, 0.f, 0.f};
  stage(0, 0);
  __syncthreads();

  for (int c = 0; c < Tt / 32; ++c) {
    int cb = c & 1;
    if (c + 1 < Tt / 32) stage(c + 1, cb ^ 1);
    // per-step scalars cr = kka.r, kr = kp.r (8 threads per step)
    {
      int stt = tid >> 3, j = tid & 7;
      const float* ka = &buf[cb][3][stt][j * 8];
      const float* rr = &buf[cb][2][stt][j * 8];
      const float* kp = &buf[cb][4][stt][j * 8];
      float cr = 0.f, kr = 0.f;
#pragma unroll
      for (int i = 0; i < 8; ++i) {
        cr = fmaf(ka[i], rr[i], cr);
        kr = fmaf(kp[i], rr[i], kr);
      }
      cr += __shfl_xor(cr, 1, 64); kr += __shfl_xor(kr, 1, 64);
      cr += __shfl_xor(cr, 2, 64); kr += __shfl_xor(kr, 2, 64);
      cr += __shfl_xor(cr, 4, 64); kr += __shfl_xor(kr, 4, 64);
      if (j == 0) { scal[cb][stt][0] = cr; scal[cb][stt][1] = kr; }
    }
    __syncthreads();
    size_t obase = rowbase + (size_t)(c * 32) * Dd + row;
#pragma unroll 4
    for (int tt = 0; tt < 32; ++tt) {
      f32x4 kk = *(const f32x4*)&buf[cb][0][tt][koff];
      f32x4 wd = *(const f32x4*)&buf[cb][1][tt][koff];
      f32x4 r4 = *(const f32x4*)&buf[cb][2][tt][koff];
      f32x4 ka = *(const f32x4*)&buf[cb][3][tt][koff];
      f32x4 kp = *(const f32x4*)&buf[cb][4][tt][koff];
      float vt = vtb[cb][tt][wid * 4 + vq];
      float cr = scal[cb][tt][0], kr = scal[cb][tt][1];
      // two dots off old S (parallel chains)
      float sab = dot4(S, kk);
      f32x4 wr = wd * r4;
      float q = dot4(S, wr);
      sab += __shfl_xor(sab, 1, 64); q += __shfl_xor(q, 1, 64);
      sab += __shfl_xor(sab, 2, 64); q += __shfl_xor(q, 2, 64);
      sab += __shfl_xor(sab, 16, 64); q += __shfl_xor(q, 16, 64);
      sab += __shfl_xor(sab, 32, 64); q += __shfl_xor(q, 32, 64);
      // state update: S = S*wd - sab*ka + vt*kp
      f32x4 u = vt * kp;
#pragma unroll
      for (int j = 0; j < 4; ++j) u[j] = fmaf(-sab, ka[j], u[j]);
#pragma unroll
      for (int j = 0; j < 4; ++j) S[j] = fmaf(S[j], wd[j], u[j]);
      // output (off critical chain)
      float o = fmaf(vt, kr, fmaf(-sab, cr, q));
      if (kq == 0) O[obase + (size_t)tt * Dd] = o;
    }
    __syncthreads();
  }
}

// ---------------- per-head groupnorm + bonus + gate -> bf16 ----------------
__global__ __launch_bounds__(256) void k_gn_gate(
    const float* __restrict__ O, const float* __restrict__ R, const float* __restrict__ KP,
    const float* __restrict__ V, const float* __restrict__ G,
    const float* __restrict__ r_k, const float* __restrict__ gn_w, const float* __restrict__ gn_b,
    u16* __restrict__ GT) {
  int row = blockIdx.x;
  int tid = threadIdx.x;
  int col = tid * 4;
  size_t idx = (size_t)row * Dd + col;
  f32x4 o = *(const f32x4*)(O + idx), r = *(const f32x4*)(R + idx),
        kp = *(const f32x4*)(KP + idx), v = *(const f32x4*)(V + idx),
        g = *(const f32x4*)(G + idx);
  f32x4 rk = *(const f32x4*)(r_k + col), gw = *(const f32x4*)(gn_w + col),
        gb = *(const f32x4*)(gn_b + col);
  float so = 0, so2 = 0, sb = 0;
#pragma unroll
  for (int j = 0; j < 4; ++j) {
    so += o[j]; so2 += o[j] * o[j]; sb += r[j] * kp[j] * rk[j];
  }
#pragma unroll
  for (int m = 1; m < 16; m <<= 1) {
    so += __shfl_xor(so, m, 64);
    so2 += __shfl_xor(so2, m, 64);
    sb += __shfl_xor(sb, m, 64);
  }
  float mu = so * (1.f / 64.f);
  float var = so2 * (1.f / 64.f) - mu * mu;
  float rs = rsqrtf(var + 64e-5f);
#pragma unroll
  for (int j = 0; j < 4; ++j) {
    float on = (o[j] - mu) * rs * gw[j] + gb[j] + sb * v[j];
    GT[idx + j] = f2bf(on * g[j]);
  }
}

// ---------------- plain LN -> bf16 ----------------
__global__ __launch_bounds__(256) void k_ln(
    const float* __restrict__ X, const float* __restrict__ w, const float* __restrict__ bias,
    u16* __restrict__ OUT) {
  int row = blockIdx.x;
  int tid = threadIdx.x;
  int col = tid * 4;
  size_t idx = (size_t)row * Dd + col;
  f32x4 c = *(const f32x4*)(X + idx);
  float s1 = 0, s2 = 0;
#pragma unroll
  for (int j = 0; j < 4; ++j) { s1 += c[j]; s2 += c[j] * c[j]; }
#pragma unroll
  for (int m = 1; m < 64; m <<= 1) { s1 += __shfl_xor(s1, m, 64); s2 += __shfl_xor(s2, m, 64); }
  __shared__ float red[4][2];
  int wid = tid >> 6;
  if ((tid & 63) == 0) { red[wid][0] = s1; red[wid][1] = s2; }
  __syncthreads();
  s1 = red[0][0] + red[1][0] + red[2][0] + red[3][0];
  s2 = red[0][1] + red[1][1] + red[2][1] + red[3][1];
  const float invD = 1.f / (float)Dd;
  float mc = s1 * invD;
  float rc = rsqrtf(s2 * invD - mc * mc + 1e-5f);
#pragma unroll
  for (int j = 0; j < 4; ++j)
    OUT[idx + j] = f2bf((c[j] - mc) * rc * w[col + j] + bias[col + j]);
}

extern "C" void kernel_launch(void* const* d_in, const int* in_sizes, int n_in,
                              void* d_out, int out_size, void* d_ws, size_t ws_size,
                              hipStream_t stream) {
  const float* x    = (const float*)d_in[0];
  const float* ln1w = (const float*)d_in[1];
  const float* ln1b = (const float*)d_in[2];
  const float* ln2w = (const float*)d_in[3];
  const float* ln2b = (const float*)d_in[4];
  const float* xr_c = (const float*)d_in[5];
  const float* xw_c = (const float*)d_in[6];
  const float* xk_c = (const float*)d_in[7];
  const float* xv_c = (const float*)d_in[8];
  const float* xa_c = (const float*)d_in[9];
  const float* xg_c = (const float*)d_in[10];
  const float* Wr   = (const float*)d_in[11];
  const float* Wk   = (const float*)d_in[12];
  const float* Wv   = (const float*)d_in[13];
  const float* w0   = (const float*)d_in[14];
  const float* w1   = (const float*)d_in[15];
  const float* w2   = (const float*)d_in[16];
  const float* a0   = (const float*)d_in[17];
  const float* a1   = (const float*)d_in[18];
  const float* a2   = (const float*)d_in[19];
  const float* g1   = (const float*)d_in[20];
  const float* g2   = (const float*)d_in[21];
  const float* k_k  = (const float*)d_in[22];
  const float* k_a  = (const float*)d_in[23];
  const float* r_k  = (const float*)d_in[24];
  const float* gnw  = (const float*)d_in[25];
  const float* gnb  = (const float*)d_in[26];
  const float* Wo   = (const float*)d_in[27];
  const float* mlpw = (const float*)d_in[28];
  const float* mlpb = (const float*)d_in[29];

  char* ws = (char*)d_ws;
  const size_t MBy = 1024 * 1024;
  u16* WT_R  = (u16*)(ws + 0 * MBy);
  u16* WT_K  = (u16*)(ws + 2 * MBy);
  u16* WT_V  = (u16*)(ws + 4 * MBy);
  u16* WT_O  = (u16*)(ws + 6 * MBy);
  u16* WT_M  = (u16*)(ws + 8 * MBy);
  u16* WT_w1 = (u16*)(ws + 10 * MBy);
  u16* WT_a1 = (u16*)(ws + 10 * MBy + 128 * 1024);
  u16* WT_g1 = (u16*)(ws + 10 * MBy + 256 * 1024);
  u16* WT_w2 = (u16*)(ws + 10 * MBy + 512 * 1024);
  u16* WT_a2 = (u16*)(ws + 10 * MBy + 640 * 1024);
  u16* WT_g2 = (u16*)(ws + 10 * MBy + 768 * 1024);
  u16* XR = (u16*)(ws + 12 * MBy);
  u16* XW = (u16*)(ws + 20 * MBy);
  u16* XK = (u16*)(ws + 28 * MBy);
  u16* XV = (u16*)(ws + 36 * MBy);
  u16* XA = (u16*)(ws + 44 * MBy);
  u16* XG = (u16*)(ws + 52 * MBy);
  float* Rf   = (float*)(ws + 60 * MBy);
  float* KRAW = (float*)(ws + 76 * MBy);
  float* WDf  = (float*)(ws + 92 * MBy);
  float* Af   = (float*)(ws + 108 * MBy);
  float* Gf   = (float*)(ws + 124 * MBy);
  // overlays
  float* KKf  = (float*)(ws + 12 * MBy);
  float* KKAf = (float*)(ws + 28 * MBy);
  float* KPf  = (float*)(ws + 44 * MBy);
  float* Of   = (float*)(ws + 76 * MBy);   // over KRAW (dead after prep)
  float* X1   = (float*)(ws + 92 * MBy);   // over WDf (dead after scan)
  u16* GT  = (u16*)(ws + 108 * MBy);       // over Af  (dead after prep)
  u16* XN2 = (u16*)(ws + 124 * MBy);       // over Gf  (dead after gn_gate)
  u16* HW = (u16*)(ws + 140 * MBy);
  u16* HA = (u16*)(ws + 140 * MBy + 512 * 1024);
  u16* HG = (u16*)(ws + 141 * MBy);
  float* OUT_X = (float*)d_out;
  float* OUT_V = (float*)d_out + (size_t)Mrows * Dd;

  dim3 blk(256);
  k_transpose_bf16<<<dim3(32, 32), blk, 0, stream>>>(Wr, WT_R, 1024, 1024);
  k_transpose_bf16<<<dim3(32, 32), blk, 0, stream>>>(Wk, WT_K, 1024, 1024);
  k_transpose_bf16<<<dim3(32, 32), blk, 0, stream>>>(Wv, WT_V, 1024, 1024);
  k_transpose_bf16<<<dim3(32, 32), blk, 0, stream>>>(Wo, WT_O, 1024, 1024);
  k_transpose_bf16<<<dim3(32, 32), blk, 0, stream>>>(mlpw, WT_M, 1024, 1024);
  k_transpose_bf16<<<dim3(2, 32), blk, 0, stream>>>(w1, WT_w1, 1024, 64);
  k_transpose_bf16<<<dim3(2, 32), blk, 0, stream>>>(a1, WT_a1, 1024, 64);
  k_transpose_bf16<<<dim3(4, 32), blk, 0, stream>>>(g1, WT_g1, 1024, 128);
  k_transpose_bf16<<<dim3(32, 2), blk, 0, stream>>>(w2, WT_w2, 64, 1024);
  k_transpose_bf16<<<dim3(32, 2), blk, 0, stream>>>(a2, WT_a2, 64, 1024);
  k_transpose_bf16<<<dim3(32, 4), blk, 0, stream>>>(g2, WT_g2, 128, 1024);

  k_ln_shift<<<Mrows, blk, 0, stream>>>(x, ln1w, ln1b, xr_c, xw_c, xk_c, xv_c, xa_c, xg_c,
                                        XR, XW, XK, XV, XA, XG);

  k_gemm_bt<128, 0><<<dim3(8, 32), blk, 0, stream>>>(XR, WT_R, Rf, nullptr, nullptr, nullptr, 1024, 1024);
  k_gemm_bt<128, 0><<<dim3(8, 32), blk, 0, stream>>>(XK, WT_K, KRAW, nullptr, nullptr, nullptr, 1024, 1024);
  k_gemm_bt<128, 0><<<dim3(8, 32), blk, 0, stream>>>(XV, WT_V, OUT_V, nullptr, nullptr, nullptr, 1024, 1024);
  k_gemm_bt<64, 1><<<dim3(1, 32), blk, 0, stream>>>(XW, WT_w1, nullptr, HW, nullptr, nullptr, 64, 1024);
  k_gemm_bt<64, 3><<<dim3(1, 32), blk, 0, stream>>>(XA, WT_a1, nullptr, HA, nullptr, nullptr, 64, 1024);
  k_gemm_bt<128, 2><<<dim3(1, 32), blk, 0, stream>>>(XG, WT_g1, nullptr, HG, nullptr, nullptr, 128, 1024);
  k_gemm_bt<128, 4><<<dim3(8, 32), blk, 0, stream>>>(HW, WT_w2, WDf, nullptr, w0, nullptr, 1024, 64);
  k_gemm_bt<128, 5><<<dim3(8, 32), blk, 0, stream>>>(HA, WT_a2, Af, nullptr, a0, nullptr, 1024, 64);
  k_gemm_bt<128, 0><<<dim3(8, 32), blk, 0, stream>>>(HG, WT_g2, Gf, nullptr, nullptr, nullptr, 1024, 128);

  k_prep<<<Mrows, blk, 0, stream>>>(KRAW, Af, k_k, k_a, KKf, KKAf, KPf);
  k_scan<<<256, blk, 0, stream>>>(Rf, WDf, KPf, KKf, KKAf, OUT_V, Of);
  k_gn_gate<<<Mrows, blk, 0, stream>>>(Of, Rf, KPf, OUT_V, Gf, r_k, gnw, gnb, GT);
  k_gemm_bt<128, 6><<<dim3(8, 32), blk, 0, stream>>>(GT, WT_O, X1, nullptr, nullptr, x, 1024, 1024);
  k_ln<<<Mrows, blk, 0, stream>>>(X1, ln2w, ln2b, XN2);
  k_gemm_bt<128, 7><<<dim3(8, 32), blk, 0, stream>>>(XN2, WT_M, OUT_X, nullptr, mlpb, X1, 1024, 1024);
}

// Round 3
// 480.088 us; speedup vs baseline: 1.6578x; 1.2837x over previous
//
#include <hip/hip_runtime.h>
#include <hip/hip_bf16.h>
#include <cstdint>

typedef unsigned short u16;
typedef __attribute__((__ext_vector_type__(4))) float f32x4;
typedef __attribute__((__ext_vector_type__(8))) __bf16 bf16x8;

#define DEV __device__ __forceinline__

static constexpr int Tt = 1024, Dd = 1024;
static constexpr int Mrows = 4096;  // B*T

DEV u16 f2bf(float f) {
  uint32_t u = __float_as_uint(f);
  u += 0x7fffu + ((u >> 16) & 1u);
  return (u16)(u >> 16);
}

DEV void gload_lds16(const void* g, void* l) {
  __builtin_amdgcn_global_load_lds(
      (__attribute__((address_space(1))) void*)(g),
      (__attribute__((address_space(3))) void*)(l), 16, 0, 0);
}

DEV float dot4(f32x4 a, f32x4 b) {
  float p01 = fmaf(a[1], b[1], a[0] * b[0]);
  float p23 = fmaf(a[3], b[3], a[2] * b[2]);
  return p01 + p23;
}

// 16-lane in-row sum reduction, all DPP (VALU-speed, no DS ops).
DEV float red16(float x) {
  x += __int_as_float(__builtin_amdgcn_update_dpp(0, __float_as_int(x), 0xB1, 0xF, 0xF, true));   // xor1 quad_perm
  x += __int_as_float(__builtin_amdgcn_update_dpp(0, __float_as_int(x), 0x4E, 0xF, 0xF, true));   // xor2 quad_perm
  x += __int_as_float(__builtin_amdgcn_update_dpp(0, __float_as_int(x), 0x141, 0xF, 0xF, true));  // row_half_mirror
  x += __int_as_float(__builtin_amdgcn_update_dpp(0, __float_as_int(x), 0x140, 0xF, 0xF, true));  // row_mirror
  return x;
}

// ---------------- fused transpose fp32 [K,N] -> bf16 [N,K], 11 matrices ----------------
struct TransDesc {
  const float* src[11];
  u16* dst[11];
  int K[11];
  int N[11];
};

__global__ __launch_bounds__(256) void k_transpose_all(TransDesc td) {
  int z = blockIdx.z;
  int K = td.K[z], N = td.N[z];
  int n0 = blockIdx.x * 32, k0 = blockIdx.y * 32;
  if (n0 >= N || k0 >= K) return;
  const float* W = td.src[z];
  u16* Wt = td.dst[z];
  __shared__ float tile[32][33];
  int c = threadIdx.x & 31, r0 = threadIdx.x >> 5;
#pragma unroll
  for (int i = 0; i < 4; ++i) {
    int r = r0 + i * 8;
    tile[r][c] = W[(size_t)(k0 + r) * N + (n0 + c)];
  }
  __syncthreads();
#pragma unroll
  for (int i = 0; i < 4; ++i) {
    int r = r0 + i * 8;
    Wt[(size_t)(n0 + r) * K + (k0 + c)] = f2bf(tile[c][r]);
  }
}

// ---------------- LN1 + token shift + 6 mixes -> bf16 ----------------
__global__ __launch_bounds__(256) void k_ln_shift(
    const float* __restrict__ x, const float* __restrict__ w, const float* __restrict__ bias,
    const float* __restrict__ cr, const float* __restrict__ cw, const float* __restrict__ ck,
    const float* __restrict__ cv, const float* __restrict__ ca, const float* __restrict__ cg,
    u16* __restrict__ XR, u16* __restrict__ XW, u16* __restrict__ XK,
    u16* __restrict__ XV, u16* __restrict__ XA, u16* __restrict__ XG) {
  int row = blockIdx.x;
  int t = row & (Tt - 1);
  int tid = threadIdx.x;
  int col = tid * 4;
  const float* xc = x + (size_t)row * Dd + col;
  f32x4 c = *(const f32x4*)xc;
  f32x4 p = {0.f, 0.f, 0.f, 0.f};
  bool hasprev = (t != 0);
  if (hasprev) p = *(const f32x4*)(xc - Dd);
  float s1 = 0, s2 = 0, s3 = 0, s4 = 0;
#pragma unroll
  for (int j = 0; j < 4; ++j) {
    s1 += c[j]; s2 += c[j] * c[j];
    s3 += p[j]; s4 += p[j] * p[j];
  }
#pragma unroll
  for (int m = 1; m < 64; m <<= 1) {
    s1 += __shfl_xor(s1, m, 64); s2 += __shfl_xor(s2, m, 64);
    s3 += __shfl_xor(s3, m, 64); s4 += __shfl_xor(s4, m, 64);
  }
  __shared__ float red[4][4];
  int wid = tid >> 6;
  if ((tid & 63) == 0) { red[wid][0] = s1; red[wid][1] = s2; red[wid][2] = s3; red[wid][3] = s4; }
  __syncthreads();
  s1 = red[0][0] + red[1][0] + red[2][0] + red[3][0];
  s2 = red[0][1] + red[1][1] + red[2][1] + red[3][1];
  s3 = red[0][2] + red[1][2] + red[2][2] + red[3][2];
  s4 = red[0][3] + red[1][3] + red[2][3] + red[3][3];
  const float invD = 1.f / (float)Dd;
  float mc = s1 * invD, vc = s2 * invD - mc * mc;
  float rc = rsqrtf(vc + 1e-5f);
  float mp = s3 * invD, vp = s4 * invD - mp * mp;
  float rp = rsqrtf(vp + 1e-5f);
  size_t ob = (size_t)row * Dd + col;
#pragma unroll
  for (int j = 0; j < 4; ++j) {
    int cc = col + j;
    float wj = w[cc], bj = bias[cc];
    float xn = (c[j] - mc) * rc * wj + bj;
    float xp = hasprev ? ((p[j] - mp) * rp * wj + bj) : 0.f;
    float d = xp - xn;
    XR[ob + j] = f2bf(xn + d * cr[cc]);
    XW[ob + j] = f2bf(xn + d * cw[cc]);
    XK[ob + j] = f2bf(xn + d * ck[cc]);
    XV[ob + j] = f2bf(xn + d * cv[cc]);
    XA[ob + j] = f2bf(xn + d * ca[cc]);
    XG[ob + j] = f2bf(xn + d * cg[cc]);
  }
}

// ---------------- bf16 MFMA GEMM: C[M,N] = A[M,K] @ Bt[N,K]^T ----------------
// EPI: 0=f32  1=tanh->bf16  2=sigmoid->bf16  3=bf16
//      4=exp(-softplus(-(w0+y)))-0.5 == e^-.5*sigmoid(w0+y) ->f32
//      5=sigmoid(a0+y)->f32  6=y+res->f32  7=y+bias+res->f32
template <int BN, int EPI>
__global__ __launch_bounds__(256) void k_gemm_bt(
    const u16* __restrict__ A, const u16* __restrict__ Bt,
    float* __restrict__ Cf, u16* __restrict__ Cb,
    const float* __restrict__ aux, const float* __restrict__ res,
    int Ndim, int K) {
  constexpr int BM = 128;
  constexpr int MR = 4;
  constexpr int NR = BN / 32;
  __shared__ __align__(16) u16 lsA[BM * 32];
  __shared__ __align__(16) u16 lsB[BN * 32];
  int tid = threadIdx.x;
  int wid = tid >> 6, lane = tid & 63;
  int wr = wid >> 1, wc = wid & 1;
  int lrow = lane & 15, lk = lane >> 4;
  int m0 = blockIdx.y * BM, n0 = blockIdx.x * BN;
  f32x4 acc[MR][NR];
#pragma unroll
  for (int m = 0; m < MR; ++m)
#pragma unroll
    for (int n = 0; n < NR; ++n) acc[m][n] = (f32x4){0.f, 0.f, 0.f, 0.f};

  for (int kt = 0; kt < K; kt += 32) {
#pragma unroll
    for (int u = 0; u < BM / 64; ++u) {
      int e = u * 256 + tid;
      int row = e >> 2, kc = (e & 3) * 8;
      gload_lds16(A + (size_t)(m0 + row) * K + kt + kc, lsA + (size_t)(u * 256 + wid * 64) * 8);
    }
#pragma unroll
    for (int u = 0; u < BN / 64; ++u) {
      int e = u * 256 + tid;
      int row = e >> 2, kc = (e & 3) * 8;
      gload_lds16(Bt + (size_t)(n0 + row) * K + kt + kc, lsB + (size_t)(u * 256 + wid * 64) * 8);
    }
    __syncthreads();
    bf16x8 af[MR], bfv[NR];
#pragma unroll
    for (int m = 0; m < MR; ++m)
      af[m] = *(const bf16x8*)&lsA[(wr * 64 + m * 16 + lrow) * 32 + lk * 8];
#pragma unroll
    for (int n = 0; n < NR; ++n)
      bfv[n] = *(const bf16x8*)&lsB[(wc * (BN / 2) + n * 16 + lrow) * 32 + lk * 8];
#pragma unroll
    for (int m = 0; m < MR; ++m)
#pragma unroll
      for (int n = 0; n < NR; ++n)
        acc[m][n] = __builtin_amdgcn_mfma_f32_16x16x32_bf16(af[m], bfv[n], acc[m][n], 0, 0, 0);
    __syncthreads();
  }
#pragma unroll
  for (int m = 0; m < MR; ++m) {
    int rbase = m0 + wr * 64 + m * 16 + lk * 4;
#pragma unroll
    for (int n = 0; n < NR; ++n) {
      int col = n0 + wc * (BN / 2) + n * 16 + lrow;
#pragma unroll
      for (int j = 0; j < 4; ++j) {
        float v = acc[m][n][j];
        size_t idx = (size_t)(rbase + j) * Ndim + col;
        if constexpr (EPI == 0) { Cf[idx] = v; }
        else if constexpr (EPI == 1) { Cb[idx] = f2bf(tanhf(v)); }
        else if constexpr (EPI == 2) { Cb[idx] = f2bf(1.f / (1.f + __expf(-v))); }
        else if constexpr (EPI == 3) { Cb[idx] = f2bf(v); }
        else if constexpr (EPI == 4) { Cf[idx] = 0.60653065971f / (1.f + __expf(-(aux[col] + v))); }
        else if constexpr (EPI == 5) { Cf[idx] = 1.f / (1.f + __expf(-(aux[col] + v))); }
        else if constexpr (EPI == 6) { Cf[idx] = v + res[idx]; }
        else { Cf[idx] = v + aux[col] + res[idx]; }
      }
    }
  }
}

// ---------------- prep: kk normalize, kka, k' ----------------
__global__ __launch_bounds__(256) void k_prep(
    const float* __restrict__ KRAW, const float* __restrict__ Aa,
    const float* __restrict__ k_k, const float* __restrict__ k_a,
    float* __restrict__ KK, float* __restrict__ KKA, float* __restrict__ KP) {
  int row = blockIdx.x;
  int tid = threadIdx.x;
  int col = tid * 4;
  size_t idx = (size_t)row * Dd + col;
  f32x4 kr = *(const f32x4*)(KRAW + idx);
  f32x4 av = *(const f32x4*)(Aa + idx);
  f32x4 kkc = *(const f32x4*)(k_k + col);
  f32x4 kac = *(const f32x4*)(k_a + col);
  f32x4 kk0 = kr * kkc;
  float ss = kk0[0] * kk0[0] + kk0[1] * kk0[1] + kk0[2] * kk0[2] + kk0[3] * kk0[3];
#pragma unroll
  for (int m = 1; m < 16; m <<= 1) ss += __shfl_xor(ss, m, 64);
  float inv = 1.f / fmaxf(sqrtf(ss), 1e-12f);
  f32x4 kk = kk0 * inv;
  f32x4 one = {1.f, 1.f, 1.f, 1.f};
  *(f32x4*)(KK + idx) = kk;
  *(f32x4*)(KKA + idx) = kk * av;
  *(f32x4*)(KP + idx) = kr * (one + (av - one) * kac);
}

// ---------------- sequential delta-rule scan, v-split, DPP reduce ----------------
// 256 wgs = 64 (b,h) x 4 v-groups of 16 rows. 256T = 4 waves x 4 rows.
// lane: kq = lane&15 (k quad), vq = lane>>4 (row within wave).
// k-reduce is fully in-row: DPP xor1, xor2, half_mirror, mirror.
// Per-lane state: S[row][kq*4 .. kq*4+4) as one f32x4.
__global__ __launch_bounds__(256) void k_scan(
    const float* __restrict__ R, const float* __restrict__ WD, const float* __restrict__ KP,
    const float* __restrict__ KK, const float* __restrict__ KKA, const float* __restrict__ V,
    float* __restrict__ O) {
  __shared__ __align__(16) float buf[2][5][32][64];  // KK,WD,R,KKA,KP
  __shared__ __align__(16) float vtb[2][32][16];
  // XCD-chunked swizzle: 4 v-groups of one (b,h) land on the same XCD.
  int sw = (blockIdx.x & 7) * 32 + (blockIdx.x >> 3);
  int bh = sw >> 2, vg = sw & 3;
  int b = bh >> 4, h = bh & 15;
  int tid = threadIdx.x;
  int wid = tid >> 6, lane = tid & 63;
  int kq = lane & 15;
  int vq = lane >> 4;
  int row = vg * 16 + wid * 4 + vq;       // v in [0,64)
  int koff = kq * 4;
  size_t rowbase = ((size_t)b * Tt) * Dd + h * 64;

  const float* ptrs[5] = {KK, WD, R, KKA, KP};
  auto stage = [&](int c, int nb) {
#pragma unroll
    for (int arr = 0; arr < 5; ++arr) {
#pragma unroll
      for (int u = 0; u < 2; ++u) {
        int e = u * 256 + tid;
        int tt = e >> 4, k4 = (e & 15) * 4;
        gload_lds16(ptrs[arr] + rowbase + (size_t)(c * 32 + tt) * Dd + k4,
                    &buf[nb][arr][0][0] + (size_t)e * 4);
      }
    }
    if (tid < 128) {
      gload_lds16(V + rowbase + (size_t)(c * 32 + (tid >> 2)) * Dd + vg * 16 + (tid & 3) * 4,
                  &vtb[nb][0][0] + (size_t)tid * 4);
    }
  };

  f32x4 S = {0.f, 0.f, 0.f, 0.f};
  stage(0, 0);
  __syncthreads();

  for (int c = 0; c < Tt / 32; ++c) {
    int cb = c & 1;
    if (c + 1 < Tt / 32) stage(c + 1, cb ^ 1);
    size_t obase = rowbase + (size_t)(c * 32) * Dd + row;
#pragma unroll 4
    for (int tt = 0; tt < 32; ++tt) {
      f32x4 kk = *(const f32x4*)&buf[cb][0][tt][koff];
      f32x4 wd = *(const f32x4*)&buf[cb][1][tt][koff];
      f32x4 r4 = *(const f32x4*)&buf[cb][2][tt][koff];
      f32x4 ka = *(const f32x4*)&buf[cb][3][tt][koff];
      f32x4 kp = *(const f32x4*)&buf[cb][4][tt][koff];
      float vt = vtb[cb][tt][wid * 4 + vq];
      float sab = red16(dot4(S, kk));
      // state update: S = S*wd - sab*ka + vt*kp
      f32x4 u;
#pragma unroll
      for (int j = 0; j < 4; ++j) u[j] = fmaf(-sab, ka[j], vt * kp[j]);
#pragma unroll
      for (int j = 0; j < 4; ++j) S[j] = fmaf(S[j], wd[j], u[j]);
      // output: o = S_new . r  (side branch, off next-step chain)
      float o = red16(dot4(S, r4));
      if (kq == 0) O[obase + (size_t)tt * Dd] = o;
    }
    __syncthreads();
  }
}

// ---------------- per-head groupnorm + bonus + gate -> bf16 ----------------
__global__ __launch_bounds__(256) void k_gn_gate(
    const float* __restrict__ O, const float* __restrict__ R, const float* __restrict__ KP,
    const float* __restrict__ V, const float* __restrict__ G,
    const float* __restrict__ r_k, const float* __restrict__ gn_w, const float* __restrict__ gn_b,
    u16* __restrict__ GT) {
  int row = blockIdx.x;
  int tid = threadIdx.x;
  int col = tid * 4;
  size_t idx = (size_t)row * Dd + col;
  f32x4 o = *(const f32x4*)(O + idx), r = *(const f32x4*)(R + idx),
        kp = *(const f32x4*)(KP + idx), v = *(const f32x4*)(V + idx),
        g = *(const f32x4*)(G + idx);
  f32x4 rk = *(const f32x4*)(r_k + col), gw = *(const f32x4*)(gn_w + col),
        gb = *(const f32x4*)(gn_b + col);
  float so = 0, so2 = 0, sb = 0;
#pragma unroll
  for (int j = 0; j < 4; ++j) {
    so += o[j]; so2 += o[j] * o[j]; sb += r[j] * kp[j] * rk[j];
  }
#pragma unroll
  for (int m = 1; m < 16; m <<= 1) {
    so += __shfl_xor(so, m, 64);
    so2 += __shfl_xor(so2, m, 64);
    sb += __shfl_xor(sb, m, 64);
  }
  float mu = so * (1.f / 64.f);
  float var = so2 * (1.f / 64.f) - mu * mu;
  float rs = rsqrtf(var + 64e-5f);
#pragma unroll
  for (int j = 0; j < 4; ++j) {
    float on = (o[j] - mu) * rs * gw[j] + gb[j] + sb * v[j];
    GT[idx + j] = f2bf(on * g[j]);
  }
}

// ---------------- plain LN -> bf16 ----------------
__global__ __launch_bounds__(256) void k_ln(
    const float* __restrict__ X, const float* __restrict__ w, const float* __restrict__ bias,
    u16* __restrict__ OUT) {
  int row = blockIdx.x;
  int tid = threadIdx.x;
  int col = tid * 4;
  size_t idx = (size_t)row * Dd + col;
  f32x4 c = *(const f32x4*)(X + idx);
  float s1 = 0, s2 = 0;
#pragma unroll
  for (int j = 0; j < 4; ++j) { s1 += c[j]; s2 += c[j] * c[j]; }
#pragma unroll
  for (int m = 1; m < 64; m <<= 1) { s1 += __shfl_xor(s1, m, 64); s2 += __shfl_xor(s2, m, 64); }
  __shared__ float red[4][2];
  int wid = tid >> 6;
  if ((tid & 63) == 0) { red[wid][0] = s1; red[wid][1] = s2; }
  __syncthreads();
  s1 = red[0][0] + red[1][0] + red[2][0] + red[3][0];
  s2 = red[0][1] + red[1][1] + red[2][1] + red[3][1];
  const float invD = 1.f / (float)Dd;
  float mc = s1 * invD;
  float rc = rsqrtf(s2 * invD - mc * mc + 1e-5f);
#pragma unroll
  for (int j = 0; j < 4; ++j)
    OUT[idx + j] = f2bf((c[j] - mc) * rc * w[col + j] + bias[col + j]);
}

extern "C" void kernel_launch(void* const* d_in, const int* in_sizes, int n_in,
                              void* d_out, int out_size, void* d_ws, size_t ws_size,
                              hipStream_t stream) {
  const float* x    = (const float*)d_in[0];
  const float* ln1w = (const float*)d_in[1];
  const float* ln1b = (const float*)d_in[2];
  const float* ln2w = (const float*)d_in[3];
  const float* ln2b = (const float*)d_in[4];
  const float* xr_c = (const float*)d_in[5];
  const float* xw_c = (const float*)d_in[6];
  const float* xk_c = (const float*)d_in[7];
  const float* xv_c = (const float*)d_in[8];
  const float* xa_c = (const float*)d_in[9];
  const float* xg_c = (const float*)d_in[10];
  const float* Wr   = (const float*)d_in[11];
  const float* Wk   = (const float*)d_in[12];
  const float* Wv   = (const float*)d_in[13];
  const float* w0   = (const float*)d_in[14];
  const float* w1   = (const float*)d_in[15];
  const float* w2   = (const float*)d_in[16];
  const float* a0   = (const float*)d_in[17];
  const float* a1   = (const float*)d_in[18];
  const float* a2   = (const float*)d_in[19];
  const float* g1   = (const float*)d_in[20];
  const float* g2   = (const float*)d_in[21];
  const float* k_k  = (const float*)d_in[22];
  const float* k_a  = (const float*)d_in[23];
  const float* r_k  = (const float*)d_in[24];
  const float* gnw  = (const float*)d_in[25];
  const float* gnb  = (const float*)d_in[26];
  const float* Wo   = (const float*)d_in[27];
  const float* mlpw = (const float*)d_in[28];
  const float* mlpb = (const float*)d_in[29];

  char* ws = (char*)d_ws;
  const size_t MBy = 1024 * 1024;
  u16* WT_R  = (u16*)(ws + 0 * MBy);
  u16* WT_K  = (u16*)(ws + 2 * MBy);
  u16* WT_V  = (u16*)(ws + 4 * MBy);
  u16* WT_O  = (u16*)(ws + 6 * MBy);
  u16* WT_M  = (u16*)(ws + 8 * MBy);
  u16* WT_w1 = (u16*)(ws + 10 * MBy);
  u16* WT_a1 = (u16*)(ws + 10 * MBy + 128 * 1024);
  u16* WT_g1 = (u16*)(ws + 10 * MBy + 256 * 1024);
  u16* WT_w2 = (u16*)(ws + 10 * MBy + 512 * 1024);
  u16* WT_a2 = (u16*)(ws + 10 * MBy + 640 * 1024);
  u16* WT_g2 = (u16*)(ws + 10 * MBy + 768 * 1024);
  u16* XR = (u16*)(ws + 12 * MBy);
  u16* XW = (u16*)(ws + 20 * MBy);
  u16* XK = (u16*)(ws + 28 * MBy);
  u16* XV = (u16*)(ws + 36 * MBy);
  u16* XA = (u16*)(ws + 44 * MBy);
  u16* XG = (u16*)(ws + 52 * MBy);
  float* Rf   = (float*)(ws + 60 * MBy);
  float* KRAW = (float*)(ws + 76 * MBy);
  float* WDf  = (float*)(ws + 92 * MBy);
  float* Af   = (float*)(ws + 108 * MBy);
  float* Gf   = (float*)(ws + 124 * MBy);
  // overlays
  float* KKf  = (float*)(ws + 12 * MBy);
  float* KKAf = (float*)(ws + 28 * MBy);
  float* KPf  = (float*)(ws + 44 * MBy);
  float* Of   = (float*)(ws + 76 * MBy);   // over KRAW (dead after prep)
  float* X1   = (float*)(ws + 92 * MBy);   // over WDf (dead after scan)
  u16* GT  = (u16*)(ws + 108 * MBy);       // over Af  (dead after prep)
  u16* XN2 = (u16*)(ws + 124 * MBy);       // over Gf  (dead after gn_gate)
  u16* HW = (u16*)(ws + 140 * MBy);
  u16* HA = (u16*)(ws + 140 * MBy + 512 * 1024);
  u16* HG = (u16*)(ws + 141 * MBy);
  float* OUT_X = (float*)d_out;
  float* OUT_V = (float*)d_out + (size_t)Mrows * Dd;

  dim3 blk(256);
  TransDesc td;
  td.src[0] = Wr;   td.dst[0] = WT_R;  td.K[0] = 1024; td.N[0] = 1024;
  td.src[1] = Wk;   td.dst[1] = WT_K;  td.K[1] = 1024; td.N[1] = 1024;
  td.src[2] = Wv;   td.dst[2] = WT_V;  td.K[2] = 1024; td.N[2] = 1024;
  td.src[3] = Wo;   td.dst[3] = WT_O;  td.K[3] = 1024; td.N[3] = 1024;
  td.src[4] = mlpw; td.dst[4] = WT_M;  td.K[4] = 1024; td.N[4] = 1024;
  td.src[5] = w1;   td.dst[5] = WT_w1; td.K[5] = 1024; td.N[5] = 64;
  td.src[6] = a1;   td.dst[6] = WT_a1; td.K[6] = 1024; td.N[6] = 64;
  td.src[7] = g1;   td.dst[7] = WT_g1; td.K[7] = 1024; td.N[7] = 128;
  td.src[8] = w2;   td.dst[8] = WT_w2; td.K[8] = 64;   td.N[8] = 1024;
  td.src[9] = a2;   td.dst[9] = WT_a2; td.K[9] = 64;   td.N[9] = 1024;
  td.src[10] = g2;  td.dst[10] = WT_g2; td.K[10] = 128; td.N[10] = 1024;
  k_transpose_all<<<dim3(32, 32, 11), blk, 0, stream>>>(td);

  k_ln_shift<<<Mrows, blk, 0, stream>>>(x, ln1w, ln1b, xr_c, xw_c, xk_c, xv_c, xa_c, xg_c,
                                        XR, XW, XK, XV, XA, XG);

  k_gemm_bt<128, 0><<<dim3(8, 32), blk, 0, stream>>>(XR, WT_R, Rf, nullptr, nullptr, nullptr, 1024, 1024);
  k_gemm_bt<128, 0><<<dim3(8, 32), blk, 0, stream>>>(XK, WT_K, KRAW, nullptr, nullptr, nullptr, 1024, 1024);
  k_gemm_bt<128, 0><<<dim3(8, 32), blk, 0, stream>>>(XV, WT_V, OUT_V, nullptr, nullptr, nullptr, 1024, 1024);
  k_gemm_bt<64, 1><<<dim3(1, 32), blk, 0, stream>>>(XW, WT_w1, nullptr, HW, nullptr, nullptr, 64, 1024);
  k_gemm_bt<64, 3><<<dim3(1, 32), blk, 0, stream>>>(XA, WT_a1, nullptr, HA, nullptr, nullptr, 64, 1024);
  k_gemm_bt<128, 2><<<dim3(1, 32), blk, 0, stream>>>(XG, WT_g1, nullptr, HG, nullptr, nullptr, 128, 1024);
  k_gemm_bt<128, 4><<<dim3(8, 32), blk, 0, stream>>>(HW, WT_w2, WDf, nullptr, w0, nullptr, 1024, 64);
  k_gemm_bt<128, 5><<<dim3(8, 32), blk, 0, stream>>>(HA, WT_a2, Af, nullptr, a0, nullptr, 1024, 64);
  k_gemm_bt<128, 0><<<dim3(8, 32), blk, 0, stream>>>(HG, WT_g2, Gf, nullptr, nullptr, nullptr, 1024, 128);

  k_prep<<<Mrows, blk, 0, stream>>>(KRAW, Af, k_k, k_a, KKf, KKAf, KPf);
  k_scan<<<256, blk, 0, stream>>>(Rf, WDf, KPf, KKf, KKAf, OUT_V, Of);
  k_gn_gate<<<Mrows, blk, 0, stream>>>(Of, Rf, KPf, OUT_V, Gf, r_k, gnw, gnb, GT);
  k_gemm_bt<128, 6><<<dim3(8, 32), blk, 0, stream>>>(GT, WT_O, X1, nullptr, nullptr, x, 1024, 1024);
  k_ln<<<Mrows, blk, 0, stream>>>(X1, ln2w, ln2b, XN2);
  k_gemm_bt<128, 7><<<dim3(8, 32), blk, 0, stream>>>(XN2, WT_M, OUT_X, nullptr, mlpb, X1, 1024, 1024);
}

// Round 4
// 458.523 us; speedup vs baseline: 1.7358x; 1.0470x over previous
//
#include <hip/hip_runtime.h>
#include <hip/hip_bf16.h>
#include <cstdint>

typedef unsigned short u16;
typedef __attribute__((__ext_vector_type__(4))) float f32x4;
typedef __attribute__((__ext_vector_type__(8))) __bf16 bf16x8;

#define DEV __device__ __forceinline__

static constexpr int Tt = 1024, Dd = 1024;
static constexpr int Mrows = 4096;  // B*T

DEV u16 f2bf(float f) {
  uint32_t u = __float_as_uint(f);
  u += 0x7fffu + ((u >> 16) & 1u);
  return (u16)(u >> 16);
}

DEV void gload_lds16(const void* g, void* l) {
  __builtin_amdgcn_global_load_lds(
      (__attribute__((address_space(1))) void*)(g),
      (__attribute__((address_space(3))) void*)(l), 16, 0, 0);
}

DEV float dot4(f32x4 a, f32x4 b) {
  float p01 = fmaf(a[1], b[1], a[0] * b[0]);
  float p23 = fmaf(a[3], b[3], a[2] * b[2]);
  return p01 + p23;
}

// 16-lane in-row sum reduction, all DPP (VALU-speed, no DS ops).
DEV float red16(float x) {
  x += __int_as_float(__builtin_amdgcn_update_dpp(0, __float_as_int(x), 0xB1, 0xF, 0xF, true));   // xor1 quad_perm
  x += __int_as_float(__builtin_amdgcn_update_dpp(0, __float_as_int(x), 0x4E, 0xF, 0xF, true));   // xor2 quad_perm
  x += __int_as_float(__builtin_amdgcn_update_dpp(0, __float_as_int(x), 0x141, 0xF, 0xF, true));  // row_half_mirror
  x += __int_as_float(__builtin_amdgcn_update_dpp(0, __float_as_int(x), 0x140, 0xF, 0xF, true));  // row_mirror
  return x;
}

// ---------------- fused transpose fp32 [K,N] -> bf16 [N,K], 11 matrices ----------------
struct TransDesc {
  const float* src[11];
  u16* dst[11];
  int K[11];
  int N[11];
};

__global__ __launch_bounds__(256) void k_transpose_all(TransDesc td) {
  int z = blockIdx.z;
  int K = td.K[z], N = td.N[z];
  int n0 = blockIdx.x * 32, k0 = blockIdx.y * 32;
  if (n0 >= N || k0 >= K) return;
  const float* W = td.src[z];
  u16* Wt = td.dst[z];
  __shared__ float tile[32][33];
  int c = threadIdx.x & 31, r0 = threadIdx.x >> 5;
#pragma unroll
  for (int i = 0; i < 4; ++i) {
    int r = r0 + i * 8;
    tile[r][c] = W[(size_t)(k0 + r) * N + (n0 + c)];
  }
  __syncthreads();
#pragma unroll
  for (int i = 0; i < 4; ++i) {
    int r = r0 + i * 8;
    Wt[(size_t)(n0 + r) * K + (k0 + c)] = f2bf(tile[c][r]);
  }
}

// ---------------- LN1 + token shift + 6 mixes -> bf16 ----------------
__global__ __launch_bounds__(256) void k_ln_shift(
    const float* __restrict__ x, const float* __restrict__ w, const float* __restrict__ bias,
    const float* __restrict__ cr, const float* __restrict__ cw, const float* __restrict__ ck,
    const float* __restrict__ cv, const float* __restrict__ ca, const float* __restrict__ cg,
    u16* __restrict__ XR, u16* __restrict__ XW, u16* __restrict__ XK,
    u16* __restrict__ XV, u16* __restrict__ XA, u16* __restrict__ XG) {
  int row = blockIdx.x;
  int t = row & (Tt - 1);
  int tid = threadIdx.x;
  int col = tid * 4;
  const float* xc = x + (size_t)row * Dd + col;
  f32x4 c = *(const f32x4*)xc;
  f32x4 p = {0.f, 0.f, 0.f, 0.f};
  bool hasprev = (t != 0);
  if (hasprev) p = *(const f32x4*)(xc - Dd);
  float s1 = 0, s2 = 0, s3 = 0, s4 = 0;
#pragma unroll
  for (int j = 0; j < 4; ++j) {
    s1 += c[j]; s2 += c[j] * c[j];
    s3 += p[j]; s4 += p[j] * p[j];
  }
#pragma unroll
  for (int m = 1; m < 64; m <<= 1) {
    s1 += __shfl_xor(s1, m, 64); s2 += __shfl_xor(s2, m, 64);
    s3 += __shfl_xor(s3, m, 64); s4 += __shfl_xor(s4, m, 64);
  }
  __shared__ float red[4][4];
  int wid = tid >> 6;
  if ((tid & 63) == 0) { red[wid][0] = s1; red[wid][1] = s2; red[wid][2] = s3; red[wid][3] = s4; }
  __syncthreads();
  s1 = red[0][0] + red[1][0] + red[2][0] + red[3][0];
  s2 = red[0][1] + red[1][1] + red[2][1] + red[3][1];
  s3 = red[0][2] + red[1][2] + red[2][2] + red[3][2];
  s4 = red[0][3] + red[1][3] + red[2][3] + red[3][3];
  const float invD = 1.f / (float)Dd;
  float mc = s1 * invD, vc = s2 * invD - mc * mc;
  float rc = rsqrtf(vc + 1e-5f);
  float mp = s3 * invD, vp = s4 * invD - mp * mp;
  float rp = rsqrtf(vp + 1e-5f);
  size_t ob = (size_t)row * Dd + col;
#pragma unroll
  for (int j = 0; j < 4; ++j) {
    int cc = col + j;
    float wj = w[cc], bj = bias[cc];
    float xn = (c[j] - mc) * rc * wj + bj;
    float xp = hasprev ? ((p[j] - mp) * rp * wj + bj) : 0.f;
    float d = xp - xn;
    XR[ob + j] = f2bf(xn + d * cr[cc]);
    XW[ob + j] = f2bf(xn + d * cw[cc]);
    XK[ob + j] = f2bf(xn + d * ck[cc]);
    XV[ob + j] = f2bf(xn + d * cv[cc]);
    XA[ob + j] = f2bf(xn + d * ca[cc]);
    XG[ob + j] = f2bf(xn + d * cg[cc]);
  }
}

// ---------------- bf16 MFMA GEMM: C[M,N] = A[M,K] @ Bt[N,K]^T ----------------
// EPI: 0=f32  1=tanh->bf16  2=sigmoid->bf16  3=bf16
//      4=exp(-softplus(-(w0+y)))-0.5 == e^-.5*sigmoid(w0+y) ->f32
//      5=sigmoid(a0+y)->f32  6=y+res->f32  7=y+bias+res->f32
template <int BN, int EPI>
__global__ __launch_bounds__(256) void k_gemm_bt(
    const u16* __restrict__ A, const u16* __restrict__ Bt,
    float* __restrict__ Cf, u16* __restrict__ Cb,
    const float* __restrict__ aux, const float* __restrict__ res,
    int Ndim, int K) {
  constexpr int BM = 128;
  constexpr int MR = 4;
  constexpr int NR = BN / 32;
  __shared__ __align__(16) u16 lsA[BM * 32];
  __shared__ __align__(16) u16 lsB[BN * 32];
  int tid = threadIdx.x;
  int wid = tid >> 6, lane = tid & 63;
  int wr = wid >> 1, wc = wid & 1;
  int lrow = lane & 15, lk = lane >> 4;
  int m0 = blockIdx.y * BM, n0 = blockIdx.x * BN;
  f32x4 acc[MR][NR];
#pragma unroll
  for (int m = 0; m < MR; ++m)
#pragma unroll
    for (int n = 0; n < NR; ++n) acc[m][n] = (f32x4){0.f, 0.f, 0.f, 0.f};

  for (int kt = 0; kt < K; kt += 32) {
#pragma unroll
    for (int u = 0; u < BM / 64; ++u) {
      int e = u * 256 + tid;
      int row = e >> 2, kc = (e & 3) * 8;
      gload_lds16(A + (size_t)(m0 + row) * K + kt + kc, lsA + (size_t)(u * 256 + wid * 64) * 8);
    }
#pragma unroll
    for (int u = 0; u < BN / 64; ++u) {
      int e = u * 256 + tid;
      int row = e >> 2, kc = (e & 3) * 8;
      gload_lds16(Bt + (size_t)(n0 + row) * K + kt + kc, lsB + (size_t)(u * 256 + wid * 64) * 8);
    }
    __syncthreads();
    bf16x8 af[MR], bfv[NR];
#pragma unroll
    for (int m = 0; m < MR; ++m)
      af[m] = *(const bf16x8*)&lsA[(wr * 64 + m * 16 + lrow) * 32 + lk * 8];
#pragma unroll
    for (int n = 0; n < NR; ++n)
      bfv[n] = *(const bf16x8*)&lsB[(wc * (BN / 2) + n * 16 + lrow) * 32 + lk * 8];
#pragma unroll
    for (int m = 0; m < MR; ++m)
#pragma unroll
      for (int n = 0; n < NR; ++n)
        acc[m][n] = __builtin_amdgcn_mfma_f32_16x16x32_bf16(af[m], bfv[n], acc[m][n], 0, 0, 0);
    __syncthreads();
  }
#pragma unroll
  for (int m = 0; m < MR; ++m) {
    int rbase = m0 + wr * 64 + m * 16 + lk * 4;
#pragma unroll
    for (int n = 0; n < NR; ++n) {
      int col = n0 + wc * (BN / 2) + n * 16 + lrow;
#pragma unroll
      for (int j = 0; j < 4; ++j) {
        float v = acc[m][n][j];
        size_t idx = (size_t)(rbase + j) * Ndim + col;
        if constexpr (EPI == 0) { Cf[idx] = v; }
        else if constexpr (EPI == 1) { Cb[idx] = f2bf(tanhf(v)); }
        else if constexpr (EPI == 2) { Cb[idx] = f2bf(1.f / (1.f + __expf(-v))); }
        else if constexpr (EPI == 3) { Cb[idx] = f2bf(v); }
        else if constexpr (EPI == 4) { Cf[idx] = 0.60653065971f / (1.f + __expf(-(aux[col] + v))); }
        else if constexpr (EPI == 5) { Cf[idx] = 1.f / (1.f + __expf(-(aux[col] + v))); }
        else if constexpr (EPI == 6) { Cf[idx] = v + res[idx]; }
        else { Cf[idx] = v + aux[col] + res[idx]; }
      }
    }
  }
}

// ---------------- prep: kk normalize, kka, k' ----------------
__global__ __launch_bounds__(256) void k_prep(
    const float* __restrict__ KRAW, const float* __restrict__ Aa,
    const float* __restrict__ k_k, const float* __restrict__ k_a,
    float* __restrict__ KK, float* __restrict__ KKA, float* __restrict__ KP) {
  int row = blockIdx.x;
  int tid = threadIdx.x;
  int col = tid * 4;
  size_t idx = (size_t)row * Dd + col;
  f32x4 kr = *(const f32x4*)(KRAW + idx);
  f32x4 av = *(const f32x4*)(Aa + idx);
  f32x4 kkc = *(const f32x4*)(k_k + col);
  f32x4 kac = *(const f32x4*)(k_a + col);
  f32x4 kk0 = kr * kkc;
  float ss = kk0[0] * kk0[0] + kk0[1] * kk0[1] + kk0[2] * kk0[2] + kk0[3] * kk0[3];
#pragma unroll
  for (int m = 1; m < 16; m <<= 1) ss += __shfl_xor(ss, m, 64);
  float inv = 1.f / fmaxf(sqrtf(ss), 1e-12f);
  f32x4 kk = kk0 * inv;
  f32x4 one = {1.f, 1.f, 1.f, 1.f};
  *(f32x4*)(KK + idx) = kk;
  *(f32x4*)(KKA + idx) = kk * av;
  *(f32x4*)(KP + idx) = kr * (one + (av - one) * kac);
}

// ---------------- sequential delta-rule scan, v-split, DPP reduce, reg prefetch ----------------
// 256 wgs = 64 (b,h) x 4 v-groups of 16 rows. 256T = 4 waves x 4 rows.
// lane: kq = lane&15 (k quad), vq = lane>>4 (row within wave).
// k-reduce is fully in-row DPP. Per-lane state: one f32x4.
// 2-step-ahead register prefetch (3-slot rotating pipeline, fully unrolled).
__global__ __launch_bounds__(256) void k_scan(
    const float* __restrict__ R, const float* __restrict__ WD, const float* __restrict__ KP,
    const float* __restrict__ KK, const float* __restrict__ KKA, const float* __restrict__ V,
    float* __restrict__ O) {
  __shared__ __align__(16) float buf[2][5][32][64];  // KK,WD,R,KKA,KP
  __shared__ __align__(16) float vtb[2][32][16];
  // XCD-chunked swizzle: 4 v-groups of one (b,h) land on the same XCD.
  int sw = (blockIdx.x & 7) * 32 + (blockIdx.x >> 3);
  int bh = sw >> 2, vg = sw & 3;
  int b = bh >> 4, h = bh & 15;
  int tid = threadIdx.x;
  int wid = tid >> 6, lane = tid & 63;
  int kq = lane & 15;
  int vq = lane >> 4;
  int row = vg * 16 + wid * 4 + vq;       // v in [0,64)
  int koff = kq * 4;
  int vidx = wid * 4 + vq;
  size_t rowbase = ((size_t)b * Tt) * Dd + h * 64;

  const float* ptrs[5] = {KK, WD, R, KKA, KP};
  auto stage = [&](int c, int nb) {
#pragma unroll
    for (int arr = 0; arr < 5; ++arr) {
#pragma unroll
      for (int u = 0; u < 2; ++u) {
        int e = u * 256 + tid;
        int tt = e >> 4, k4 = (e & 15) * 4;
        gload_lds16(ptrs[arr] + rowbase + (size_t)(c * 32 + tt) * Dd + k4,
                    &buf[nb][arr][0][0] + (size_t)e * 4);
      }
    }
    if (tid < 128) {
      gload_lds16(V + rowbase + (size_t)(c * 32 + (tid >> 2)) * Dd + vg * 16 + (tid & 3) * 4,
                  &vtb[nb][0][0] + (size_t)tid * 4);
    }
  };

  f32x4 S = {0.f, 0.f, 0.f, 0.f};
  stage(0, 0);
  __syncthreads();

  for (int c = 0; c < Tt / 32; ++c) {
    int cb = c & 1;
    if (c + 1 < Tt / 32) stage(c + 1, cb ^ 1);
    size_t obase = rowbase + (size_t)(c * 32) * Dd + row;
    // 3-slot rotating register pipeline, 2 steps ahead (all indices static).
    f32x4 pkk[3], pwd[3], pr4[3], pka[3], pkp[3];
    float pvt[3];
#pragma unroll
    for (int s = 0; s < 2; ++s) {
      pkk[s] = *(const f32x4*)&buf[cb][0][s][koff];
      pwd[s] = *(const f32x4*)&buf[cb][1][s][koff];
      pr4[s] = *(const f32x4*)&buf[cb][2][s][koff];
      pka[s] = *(const f32x4*)&buf[cb][3][s][koff];
      pkp[s] = *(const f32x4*)&buf[cb][4][s][koff];
      pvt[s] = vtb[cb][s][vidx];
    }
#pragma unroll
    for (int tt = 0; tt < 32; ++tt) {
      const int s = tt % 3;
      if (tt + 2 < 32) {
        const int s2 = (tt + 2) % 3;
        pkk[s2] = *(const f32x4*)&buf[cb][0][tt + 2][koff];
        pwd[s2] = *(const f32x4*)&buf[cb][1][tt + 2][koff];
        pr4[s2] = *(const f32x4*)&buf[cb][2][tt + 2][koff];
        pka[s2] = *(const f32x4*)&buf[cb][3][tt + 2][koff];
        pkp[s2] = *(const f32x4*)&buf[cb][4][tt + 2][koff];
        pvt[s2] = vtb[cb][tt + 2][vidx];
      }
      float sab = red16(dot4(S, pkk[s]));
      f32x4 u;
#pragma unroll
      for (int j = 0; j < 4; ++j) u[j] = fmaf(-sab, pka[s][j], pvt[s] * pkp[s][j]);
#pragma unroll
      for (int j = 0; j < 4; ++j) S[j] = fmaf(S[j], pwd[s][j], u[j]);
      // output: o = S_new . r  (side branch, off next-step chain)
      float o = red16(dot4(S, pr4[s]));
      if (kq == 0) O[obase + (size_t)tt * Dd] = o;
    }
    __syncthreads();
  }
}

// ---------------- per-head groupnorm + bonus + gate -> bf16 ----------------
__global__ __launch_bounds__(256) void k_gn_gate(
    const float* __restrict__ O, const float* __restrict__ R, const float* __restrict__ KP,
    const float* __restrict__ V, const float* __restrict__ G,
    const float* __restrict__ r_k, const float* __restrict__ gn_w, const float* __restrict__ gn_b,
    u16* __restrict__ GT) {
  int row = blockIdx.x;
  int tid = threadIdx.x;
  int col = tid * 4;
  size_t idx = (size_t)row * Dd + col;
  f32x4 o = *(const f32x4*)(O + idx), r = *(const f32x4*)(R + idx),
        kp = *(const f32x4*)(KP + idx), v = *(const f32x4*)(V + idx),
        g = *(const f32x4*)(G + idx);
  f32x4 rk = *(const f32x4*)(r_k + col), gw = *(const f32x4*)(gn_w + col),
        gb = *(const f32x4*)(gn_b + col);
  float so = 0, so2 = 0, sb = 0;
#pragma unroll
  for (int j = 0; j < 4; ++j) {
    so += o[j]; so2 += o[j] * o[j]; sb += r[j] * kp[j] * rk[j];
  }
#pragma unroll
  for (int m = 1; m < 16; m <<= 1) {
    so += __shfl_xor(so, m, 64);
    so2 += __shfl_xor(so2, m, 64);
    sb += __shfl_xor(sb, m, 64);
  }
  float mu = so * (1.f / 64.f);
  float var = so2 * (1.f / 64.f) - mu * mu;
  float rs = rsqrtf(var + 64e-5f);
#pragma unroll
  for (int j = 0; j < 4; ++j) {
    float on = (o[j] - mu) * rs * gw[j] + gb[j] + sb * v[j];
    GT[idx + j] = f2bf(on * g[j]);
  }
}

// ---------------- plain LN -> bf16 ----------------
__global__ __launch_bounds__(256) void k_ln(
    const float* __restrict__ X, const float* __restrict__ w, const float* __restrict__ bias,
    u16* __restrict__ OUT) {
  int row = blockIdx.x;
  int tid = threadIdx.x;
  int col = tid * 4;
  size_t idx = (size_t)row * Dd + col;
  f32x4 c = *(const f32x4*)(X + idx);
  float s1 = 0, s2 = 0;
#pragma unroll
  for (int j = 0; j < 4; ++j) { s1 += c[j]; s2 += c[j] * c[j]; }
#pragma unroll
  for (int m = 1; m < 64; m <<= 1) { s1 += __shfl_xor(s1, m, 64); s2 += __shfl_xor(s2, m, 64); }
  __shared__ float red[4][2];
  int wid = tid >> 6;
  if ((tid & 63) == 0) { red[wid][0] = s1; red[wid][1] = s2; }
  __syncthreads();
  s1 = red[0][0] + red[1][0] + red[2][0] + red[3][0];
  s2 = red[0][1] + red[1][1] + red[2][1] + red[3][1];
  const float invD = 1.f / (float)Dd;
  float mc = s1 * invD;
  float rc = rsqrtf(s2 * invD - mc * mc + 1e-5f);
#pragma unroll
  for (int j = 0; j < 4; ++j)
    OUT[idx + j] = f2bf((c[j] - mc) * rc * w[col + j] + bias[col + j]);
}

extern "C" void kernel_launch(void* const* d_in, const int* in_sizes, int n_in,
                              void* d_out, int out_size, void* d_ws, size_t ws_size,
                              hipStream_t stream) {
  const float* x    = (const float*)d_in[0];
  const float* ln1w = (const float*)d_in[1];
  const float* ln1b = (const float*)d_in[2];
  const float* ln2w = (const float*)d_in[3];
  const float* ln2b = (const float*)d_in[4];
  const float* xr_c = (const float*)d_in[5];
  const float* xw_c = (const float*)d_in[6];
  const float* xk_c = (const float*)d_in[7];
  const float* xv_c = (const float*)d_in[8];
  const float* xa_c = (const float*)d_in[9];
  const float* xg_c = (const float*)d_in[10];
  const float* Wr   = (const float*)d_in[11];
  const float* Wk   = (const float*)d_in[12];
  const float* Wv   = (const float*)d_in[13];
  const float* w0   = (const float*)d_in[14];
  const float* w1   = (const float*)d_in[15];
  const float* w2   = (const float*)d_in[16];
  const float* a0   = (const float*)d_in[17];
  const float* a1   = (const float*)d_in[18];
  const float* a2   = (const float*)d_in[19];
  const float* g1   = (const float*)d_in[20];
  const float* g2   = (const float*)d_in[21];
  const float* k_k  = (const float*)d_in[22];
  const float* k_a  = (const float*)d_in[23];
  const float* r_k  = (const float*)d_in[24];
  const float* gnw  = (const float*)d_in[25];
  const float* gnb  = (const float*)d_in[26];
  const float* Wo   = (const float*)d_in[27];
  const float* mlpw = (const float*)d_in[28];
  const float* mlpb = (const float*)d_in[29];

  char* ws = (char*)d_ws;
  const size_t MBy = 1024 * 1024;
  u16* WT_R  = (u16*)(ws + 0 * MBy);
  u16* WT_K  = (u16*)(ws + 2 * MBy);
  u16* WT_V  = (u16*)(ws + 4 * MBy);
  u16* WT_O  = (u16*)(ws + 6 * MBy);
  u16* WT_M  = (u16*)(ws + 8 * MBy);
  u16* WT_w1 = (u16*)(ws + 10 * MBy);
  u16* WT_a1 = (u16*)(ws + 10 * MBy + 128 * 1024);
  u16* WT_g1 = (u16*)(ws + 10 * MBy + 256 * 1024);
  u16* WT_w2 = (u16*)(ws + 10 * MBy + 512 * 1024);
  u16* WT_a2 = (u16*)(ws + 10 * MBy + 640 * 1024);
  u16* WT_g2 = (u16*)(ws + 10 * MBy + 768 * 1024);
  u16* XR = (u16*)(ws + 12 * MBy);
  u16* XW = (u16*)(ws + 20 * MBy);
  u16* XK = (u16*)(ws + 28 * MBy);
  u16* XV = (u16*)(ws + 36 * MBy);
  u16* XA = (u16*)(ws + 44 * MBy);
  u16* XG = (u16*)(ws + 52 * MBy);
  float* Rf   = (float*)(ws + 60 * MBy);
  float* KRAW = (float*)(ws + 76 * MBy);
  float* WDf  = (float*)(ws + 92 * MBy);
  float* Af   = (float*)(ws + 108 * MBy);
  float* Gf   = (float*)(ws + 124 * MBy);
  // overlays
  float* KKf  = (float*)(ws + 12 * MBy);
  float* KKAf = (float*)(ws + 28 * MBy);
  float* KPf  = (float*)(ws + 44 * MBy);
  float* Of   = (float*)(ws + 76 * MBy);   // over KRAW (dead after prep)
  float* X1   = (float*)(ws + 92 * MBy);   // over WDf (dead after scan)
  u16* GT  = (u16*)(ws + 108 * MBy);       // over Af  (dead after prep)
  u16* XN2 = (u16*)(ws + 124 * MBy);       // over Gf  (dead after gn_gate)
  u16* HW = (u16*)(ws + 140 * MBy);
  u16* HA = (u16*)(ws + 140 * MBy + 512 * 1024);
  u16* HG = (u16*)(ws + 141 * MBy);
  float* OUT_X = (float*)d_out;
  float* OUT_V = (float*)d_out + (size_t)Mrows * Dd;

  dim3 blk(256);
  TransDesc td;
  td.src[0] = Wr;   td.dst[0] = WT_R;  td.K[0] = 1024; td.N[0] = 1024;
  td.src[1] = Wk;   td.dst[1] = WT_K;  td.K[1] = 1024; td.N[1] = 1024;
  td.src[2] = Wv;   td.dst[2] = WT_V;  td.K[2] = 1024; td.N[2] = 1024;
  td.src[3] = Wo;   td.dst[3] = WT_O;  td.K[3] = 1024; td.N[3] = 1024;
  td.src[4] = mlpw; td.dst[4] = WT_M;  td.K[4] = 1024; td.N[4] = 1024;
  td.src[5] = w1;   td.dst[5] = WT_w1; td.K[5] = 1024; td.N[5] = 64;
  td.src[6] = a1;   td.dst[6] = WT_a1; td.K[6] = 1024; td.N[6] = 64;
  td.src[7] = g1;   td.dst[7] = WT_g1; td.K[7] = 1024; td.N[7] = 128;
  td.src[8] = w2;   td.dst[8] = WT_w2; td.K[8] = 64;   td.N[8] = 1024;
  td.src[9] = a2;   td.dst[9] = WT_a2; td.K[9] = 64;   td.N[9] = 1024;
  td.src[10] = g2;  td.dst[10] = WT_g2; td.K[10] = 128; td.N[10] = 1024;
  k_transpose_all<<<dim3(32, 32, 11), blk, 0, stream>>>(td);

  k_ln_shift<<<Mrows, blk, 0, stream>>>(x, ln1w, ln1b, xr_c, xw_c, xk_c, xv_c, xa_c, xg_c,
                                        XR, XW, XK, XV, XA, XG);

  k_gemm_bt<128, 0><<<dim3(8, 32), blk, 0, stream>>>(XR, WT_R, Rf, nullptr, nullptr, nullptr, 1024, 1024);
  k_gemm_bt<128, 0><<<dim3(8, 32), blk, 0, stream>>>(XK, WT_K, KRAW, nullptr, nullptr, nullptr, 1024, 1024);
  k_gemm_bt<128, 0><<<dim3(8, 32), blk, 0, stream>>>(XV, WT_V, OUT_V, nullptr, nullptr, nullptr, 1024, 1024);
  k_gemm_bt<64, 1><<<dim3(1, 32), blk, 0, stream>>>(XW, WT_w1, nullptr, HW, nullptr, nullptr, 64, 1024);
  k_gemm_bt<64, 3><<<dim3(1, 32), blk, 0, stream>>>(XA, WT_a1, nullptr, HA, nullptr, nullptr, 64, 1024);
  k_gemm_bt<128, 2><<<dim3(1, 32), blk, 0, stream>>>(XG, WT_g1, nullptr, HG, nullptr, nullptr, 128, 1024);
  k_gemm_bt<128, 4><<<dim3(8, 32), blk, 0, stream>>>(HW, WT_w2, WDf, nullptr, w0, nullptr, 1024, 64);
  k_gemm_bt<128, 5><<<dim3(8, 32), blk, 0, stream>>>(HA, WT_a2, Af, nullptr, a0, nullptr, 1024, 64);
  k_gemm_bt<128, 0><<<dim3(8, 32), blk, 0, stream>>>(HG, WT_g2, Gf, nullptr, nullptr, nullptr, 1024, 128);

  k_prep<<<Mrows, blk, 0, stream>>>(KRAW, Af, k_k, k_a, KKf, KKAf, KPf);
  k_scan<<<256, blk, 0, stream>>>(Rf, WDf, KPf, KKf, KKAf, OUT_V, Of);
  k_gn_gate<<<Mrows, blk, 0, stream>>>(Of, Rf, KPf, OUT_V, Gf, r_k, gnw, gnb, GT);
  k_gemm_bt<128, 6><<<dim3(8, 32), blk, 0, stream>>>(GT, WT_O, X1, nullptr, nullptr, x, 1024, 1024);
  k_ln<<<Mrows, blk, 0, stream>>>(X1, ln2w, ln2b, XN2);
  k_gemm_bt<128, 7><<<dim3(8, 32), blk, 0, stream>>>(XN2, WT_M, OUT_X, nullptr, mlpb, X1, 1024, 1024);
}